// Round 3
// baseline (309.061 us; speedup 1.0000x reference)
//
#include <hip/hip_runtime.h>
#include <stdint.h>

#define BB 4
#define TT 2048
#define CC 1024
#define HH 16
#define HD 64
#define C3 3072
#define MM (BB*TT)   // 8192 rows

typedef __bf16 bf16_t;
typedef bf16_t bf16x8 __attribute__((ext_vector_type(8)));
typedef float f32x4 __attribute__((ext_vector_type(4)));
typedef unsigned short u16;
typedef u16 u16x8 __attribute__((ext_vector_type(8)));
typedef uint32_t u32;

// f32 -> bf16 round-to-nearest-even
static __device__ __forceinline__ u16 f2bf(float f){
  u32 u = __builtin_bit_cast(u32, f);
  u32 r = (u + 0x7fffu + ((u >> 16) & 1u)) >> 16;
  return (u16)r;
}

static __device__ __forceinline__ f32x4 mfma16(bf16x8 a, bf16x8 b, f32x4 c){
  return __builtin_amdgcn_mfma_f32_16x16x32_bf16(a, b, c, 0, 0, 0);
}

typedef __attribute__((address_space(1))) void* gas_t;
typedef __attribute__((address_space(3))) void* las_t;
static __device__ __forceinline__ void gload16(const void* g, void* l){
  __builtin_amdgcn_global_load_lds((gas_t)g, (las_t)l, 16, 0, 0);
}

// ---------------- fp32 -> bf16 conversion (vectorized) ----------------
__global__ __launch_bounds__(256) void cvt_bf16(const float* __restrict__ in,
                                                u16* __restrict__ out, int n8){
  int stride = gridDim.x * blockDim.x;
  for (int i = blockIdx.x * blockDim.x + threadIdx.x; i < n8; i += stride){
    const float4* p = (const float4*)in + (size_t)i * 2;
    float4 a = p[0], b = p[1];
    u16x8 o;
    o[0]=f2bf(a.x); o[1]=f2bf(a.y); o[2]=f2bf(a.z); o[3]=f2bf(a.w);
    o[4]=f2bf(b.x); o[5]=f2bf(b.y); o[6]=f2bf(b.z); o[7]=f2bf(b.w);
    *((u16x8*)out + i) = o;
  }
}

// ---------------- bt-GEMM: C[M,N] = A[M,K] * B[N,K]^T  (m97 structure) --------
template<int OUTBF>
__global__ __launch_bounds__(256) void gemm_bt(const u16* __restrict__ A,
                                               const u16* __restrict__ Bm,
                                               void* __restrict__ Cp,
                                               int M, int N, int K){
  __shared__ u16 As[128*32];
  __shared__ u16 Bs[128*32];
  const int tid  = threadIdx.x;
  const int lane = tid & 63;
  const int w    = tid >> 6;
  const int m0   = blockIdx.y * 128;
  const int n0   = blockIdx.x * 128;
  const int wm   = (w >> 1) * 64;
  const int wn   = (w & 1) * 64;
  const int lr   = lane & 15;
  const int lkb  = (lane >> 4) * 16;

  f32x4 acc[4][4] = {};

  const int r0 = w*32 + (lane >> 2);
  const int c8 = (lane & 3) * 8;
  const u16* gA = A  + (size_t)(m0 + r0) * K + c8;
  const u16* gB = Bm + (size_t)(n0 + r0) * K + c8;
  char* lA = (char*)As + w*2048 + lane*16;
  char* lB = (char*)Bs + w*2048 + lane*16;

  for (int k0 = 0; k0 < K; k0 += 32){
    gload16(gA + k0,                 lA);
    gload16(gA + (size_t)16*K + k0,  lA + 1024);
    gload16(gB + k0,                 lB);
    gload16(gB + (size_t)16*K + k0,  lB + 1024);
    __syncthreads();
    bf16x8 af[4], bfr[4];
    #pragma unroll
    for (int m = 0; m < 4; m++)
      af[m] = *(const bf16x8*)((const char*)As + (wm + m*16 + lr)*64 + lkb);
    #pragma unroll
    for (int n = 0; n < 4; n++)
      bfr[n] = *(const bf16x8*)((const char*)Bs + (wn + n*16 + lr)*64 + lkb);
    #pragma unroll
    for (int m = 0; m < 4; m++)
      #pragma unroll
      for (int n = 0; n < 4; n++)
        acc[m][n] = mfma16(af[m], bfr[n], acc[m][n]);
    __syncthreads();
  }

  const int cr = (lane >> 4) * 4;
  #pragma unroll
  for (int m = 0; m < 4; m++)
    #pragma unroll
    for (int n = 0; n < 4; n++)
      #pragma unroll
      for (int j = 0; j < 4; j++){
        size_t row = (size_t)(m0 + wm + m*16 + cr + j);
        size_t col = (size_t)(n0 + wn + n*16 + lr);
        if (OUTBF) ((u16*)Cp)[row*(size_t)N + col] = f2bf(acc[m][n][j]);
        else       ((float*)Cp)[row*(size_t)N + col] = acc[m][n][j];
      }
}

// ---------------- flash attention (causal), bf16 in/out ----------------
// 1024 blocks, ALL co-resident at 4 blocks/CU. Balanced qtb interleave:
// g=bid>>6 -> qtb = g even ? 15-g/2 : g/2 (heavy/light mix per CU window).
// 256 thr = 4 waves; wave w owns q rows {m*64 + w*16 + [0,16)} for m=0,1.
__global__ __launch_bounds__(256, 4) void attn_fwd(const u16* __restrict__ qkv,
                                                   u16* __restrict__ y){
  __shared__ u16 Kl[64*72];      // K tile [k][d], row stride 72 (odd*16B)
  __shared__ u16 Vt[64*72];      // V^T tile [d][k], row stride 72
  __shared__ u16 Pl[4][32*72];   // per-wave P [q32][k64], row stride 72
  const int bid = blockIdx.x;
  const int g = bid >> 6;
  const int qtb = (g & 1) ? (g >> 1) : (15 - (g >> 1));
  const int h = bid & 15, b = (bid >> 4) & 3;
  const int tid = threadIdx.x, lane = tid & 63, w = tid >> 6;
  const int lr = lane & 15, lg = lane >> 4;
  const size_t base = (size_t)b * TT * C3;
  const int q0 = qtb * 128;

  // Q fragments (A-operand): row = lr, d = ks*32 + lg*8 + j
  bf16x8 qf[2][2];
  #pragma unroll
  for (int m = 0; m < 2; m++){
    const u16* qp = qkv + base + (size_t)(q0 + m*64 + w*16 + lr) * C3 + h*HD;
    qf[m][0] = *(const bf16x8*)(qp + lg*8);
    qf[m][1] = *(const bf16x8*)(qp + 32 + lg*8);
  }

  // staging maps: K coalesced (row = tid>>3), V k-major lanes (row = tid&31)
  const int rK = tid >> 3, cK = tid & 7;
  const int rV = tid & 31, cV = tid >> 5;
  const u16* gK = qkv + base + (size_t)rK * C3 + CC   + h*HD + cK*8;
  const u16* gV = qkv + base + (size_t)rV * C3 + 2*CC + h*HD + cV*8;

  u16x8 kreg[2], vreg[2];
  kreg[0] = *(const u16x8*)(gK);
  kreg[1] = *(const u16x8*)(gK + (size_t)32*C3);
  vreg[0] = *(const u16x8*)(gV);
  vreg[1] = *(const u16x8*)(gV + (size_t)32*C3);

  f32x4 o[2][4] = {};
  float mj[2][4], lj[2][4];
  #pragma unroll
  for (int m = 0; m < 2; m++)
    #pragma unroll
    for (int j = 0; j < 4; j++){ mj[m][j] = -1e30f; lj[m][j] = 0.f; }
  const float SC = 0.18033688011112042f;   // (1/8) * log2(e)

  const int ktmax = 2*qtb + 1;
  for (int kt = 0; kt <= ktmax; kt++){
    __syncthreads();   // previous tile's LDS reads complete
    *(u16x8*)&Kl[rK*72 + cK*8] = kreg[0];
    *(u16x8*)&Kl[(rK+32)*72 + cK*8] = kreg[1];
    #pragma unroll
    for (int i = 0; i < 2; i++)
      #pragma unroll
      for (int e = 0; e < 8; e++)
        Vt[(cV*8+e)*72 + i*32 + rV] = vreg[i][e];
    __syncthreads();

    // prefetch next tile into regs (hides under compute)
    if (kt < ktmax){
      const u16* gk2 = gK + (size_t)(kt+1)*64*C3;
      const u16* gv2 = gV + (size_t)(kt+1)*64*C3;
      kreg[0] = *(const u16x8*)(gk2);
      kreg[1] = *(const u16x8*)(gk2 + (size_t)32*C3);
      vreg[0] = *(const u16x8*)(gv2);
      vreg[1] = *(const u16x8*)(gv2 + (size_t)32*C3);
    }

    // S = Q K^T : s[m][n], shared B-frags across m
    f32x4 s[2][4] = {};
    #pragma unroll
    for (int n = 0; n < 4; n++){
      bf16x8 kb0 = *(const bf16x8*)&Kl[(n*16+lr)*72 + lg*8];
      bf16x8 kb1 = *(const bf16x8*)&Kl[(n*16+lr)*72 + 32 + lg*8];
      #pragma unroll
      for (int m = 0; m < 2; m++){
        s[m][n] = mfma16(qf[m][0], kb0, s[m][n]);
        s[m][n] = mfma16(qf[m][1], kb1, s[m][n]);
      }
    }

    const bool domask = (kt >= 2*qtb);
    #pragma unroll
    for (int m = 0; m < 2; m++){
      #pragma unroll
      for (int j = 0; j < 4; j++){
        float t0 = s[m][0][j]*SC, t1 = s[m][1][j]*SC,
              t2 = s[m][2][j]*SC, t3 = s[m][3][j]*SC;
        if (domask){
          int q = q0 + m*64 + w*16 + lg*4 + j;
          int kb = kt*64 + lr;
          if (kb      > q) t0 = -1e30f;
          if (kb + 16 > q) t1 = -1e30f;
          if (kb + 32 > q) t2 = -1e30f;
          if (kb + 48 > q) t3 = -1e30f;
        }
        float tm = fmaxf(fmaxf(t0, t1), fmaxf(t2, t3));
        #pragma unroll
        for (int d = 1; d < 16; d <<= 1) tm = fmaxf(tm, __shfl_xor(tm, d, 64));
        float mo = mj[m][j];
        float mn;
        if (__all(tm <= mo)){          // T13 defer-max: no rescale needed
          mn = mo;
        } else {
          mn = fmaxf(mo, tm);
          float al = __builtin_amdgcn_exp2f(mo - mn);
          mj[m][j] = mn;
          lj[m][j] *= al;
          o[m][0][j] *= al; o[m][1][j] *= al; o[m][2][j] *= al; o[m][3][j] *= al;
        }
        float p0 = __builtin_amdgcn_exp2f(t0 - mn);
        float p1 = __builtin_amdgcn_exp2f(t1 - mn);
        float p2 = __builtin_amdgcn_exp2f(t2 - mn);
        float p3 = __builtin_amdgcn_exp2f(t3 - mn);
        float ps = (p0 + p1) + (p2 + p3);
        #pragma unroll
        for (int d = 1; d < 16; d <<= 1) ps += __shfl_xor(ps, d, 64);
        lj[m][j] += ps;
        int prow = m*16 + lg*4 + j;
        Pl[w][prow*72 +      lr] = f2bf(p0);
        Pl[w][prow*72 + 16 + lr] = f2bf(p1);
        Pl[w][prow*72 + 32 + lr] = f2bf(p2);
        Pl[w][prow*72 + 48 + lr] = f2bf(p3);
      }
    }
    asm volatile("s_waitcnt lgkmcnt(0)" ::: "memory");

    // O += P V
    #pragma unroll
    for (int ks = 0; ks < 2; ks++){
      bf16x8 pa0 = *(const bf16x8*)&Pl[w][(lr     )*72 + ks*32 + lg*8];
      bf16x8 pa1 = *(const bf16x8*)&Pl[w][(16 + lr)*72 + ks*32 + lg*8];
      #pragma unroll
      for (int n = 0; n < 4; n++){
        bf16x8 vb = *(const bf16x8*)&Vt[(n*16+lr)*72 + ks*32 + lg*8];
        o[0][n] = mfma16(pa0, vb, o[0][n]);
        o[1][n] = mfma16(pa1, vb, o[1][n]);
      }
    }
  }

  // normalize + write y (bf16)
  #pragma unroll
  for (int m = 0; m < 2; m++)
    #pragma unroll
    for (int j = 0; j < 4; j++){
      float inv = 1.0f / lj[m][j];
      size_t row = (size_t)b*TT + q0 + m*64 + w*16 + lg*4 + j;
      #pragma unroll
      for (int n = 0; n < 4; n++)
        y[row*CC + h*HD + n*16 + lr] = f2bf(o[m][n][j] * inv);
    }
}

// ---------------- launch ----------------
extern "C" void kernel_launch(void* const* d_in, const int* in_sizes, int n_in,
                              void* d_out, int out_size, void* d_ws, size_t ws_size,
                              hipStream_t stream){
  const float* x     = (const float*)d_in[0];
  const float* w_in  = (const float*)d_in[1];
  const float* w_out = (const float*)d_in[2];
  float* out = (float*)d_out;

  u16* xb   = (u16*)d_ws;                  // 8192*1024  (reused as y after GEMM1)
  u16* wib  = xb  + (size_t)MM * CC;       // 3072*1024
  u16* wob  = wib + (size_t)C3 * CC;       // 1024*1024
  u16* qkvb = wob + (size_t)CC * CC;       // 8192*3072
  u16* yb   = xb;                          // x is dead after GEMM1

  auto nblk = [](int n8){ int g = (n8 + 255) / 256; return g > 2048 ? 2048 : g; };
  cvt_bf16<<<nblk(MM*CC/8), 256, 0, stream>>>(x,     xb,  MM*CC/8);
  cvt_bf16<<<nblk(C3*CC/8), 256, 0, stream>>>(w_in,  wib, C3*CC/8);
  cvt_bf16<<<nblk(CC*CC/8), 256, 0, stream>>>(w_out, wob, CC*CC/8);

  gemm_bt<1><<<dim3(C3/128, MM/128), 256, 0, stream>>>(xb, wib, (void*)qkvb, MM, C3, CC);
  attn_fwd<<<1024, 256, 0, stream>>>(qkvb, yb);
  gemm_bt<0><<<dim3(CC/128, MM/128), 256, 0, stream>>>(yb, wob, (void*)out, MM, CC, CC);
}

// Round 4
// 248.943 us; speedup vs baseline: 1.2415x; 1.2415x over previous
//
#include <hip/hip_runtime.h>
#include <stdint.h>

#define BB 4
#define TT 2048
#define CC 1024
#define HH 16
#define HD 64
#define C3 3072
#define MM (BB*TT)   // 8192 rows

typedef __bf16 bf16_t;
typedef bf16_t bf16x8 __attribute__((ext_vector_type(8)));
typedef float f32x4 __attribute__((ext_vector_type(4)));
typedef unsigned short u16;
typedef u16 u16x8 __attribute__((ext_vector_type(8)));
typedef uint32_t u32;

// f32 -> bf16 round-to-nearest-even
static __device__ __forceinline__ u16 f2bf(float f){
  u32 u = __builtin_bit_cast(u32, f);
  u32 r = (u + 0x7fffu + ((u >> 16) & 1u)) >> 16;
  return (u16)r;
}

static __device__ __forceinline__ f32x4 mfma16(bf16x8 a, bf16x8 b, f32x4 c){
  return __builtin_amdgcn_mfma_f32_16x16x32_bf16(a, b, c, 0, 0, 0);
}

typedef __attribute__((address_space(1))) void* gas_t;
typedef __attribute__((address_space(3))) void* las_t;
static __device__ __forceinline__ void gload16(const void* g, void* l){
  __builtin_amdgcn_global_load_lds((gas_t)g, (las_t)l, 16, 0, 0);
}

// ---------------- fp32 -> bf16 conversion (vectorized) ----------------
__global__ __launch_bounds__(256) void cvt_bf16(const float* __restrict__ in,
                                                u16* __restrict__ out, int n8){
  int stride = gridDim.x * blockDim.x;
  for (int i = blockIdx.x * blockDim.x + threadIdx.x; i < n8; i += stride){
    const float4* p = (const float4*)in + (size_t)i * 2;
    float4 a = p[0], b = p[1];
    u16x8 o;
    o[0]=f2bf(a.x); o[1]=f2bf(a.y); o[2]=f2bf(a.z); o[3]=f2bf(a.w);
    o[4]=f2bf(b.x); o[5]=f2bf(b.y); o[6]=f2bf(b.z); o[7]=f2bf(b.w);
    *((u16x8*)out + i) = o;
  }
}

// ---------------- bt-GEMM: C[M,N] = A[M,K] * B[N,K]^T  (m97 structure) --------
template<int OUTBF>
__global__ __launch_bounds__(256) void gemm_bt(const u16* __restrict__ A,
                                               const u16* __restrict__ Bm,
                                               void* __restrict__ Cp,
                                               int M, int N, int K){
  __shared__ u16 As[128*32];
  __shared__ u16 Bs[128*32];
  const int tid  = threadIdx.x;
  const int lane = tid & 63;
  const int w    = tid >> 6;
  const int m0   = blockIdx.y * 128;
  const int n0   = blockIdx.x * 128;
  const int wm   = (w >> 1) * 64;
  const int wn   = (w & 1) * 64;
  const int lr   = lane & 15;
  const int lkb  = (lane >> 4) * 16;

  f32x4 acc[4][4] = {};

  const int r0 = w*32 + (lane >> 2);
  const int c8 = (lane & 3) * 8;
  const u16* gA = A  + (size_t)(m0 + r0) * K + c8;
  const u16* gB = Bm + (size_t)(n0 + r0) * K + c8;
  char* lA = (char*)As + w*2048 + lane*16;
  char* lB = (char*)Bs + w*2048 + lane*16;

  for (int k0 = 0; k0 < K; k0 += 32){
    gload16(gA + k0,                 lA);
    gload16(gA + (size_t)16*K + k0,  lA + 1024);
    gload16(gB + k0,                 lB);
    gload16(gB + (size_t)16*K + k0,  lB + 1024);
    __syncthreads();
    bf16x8 af[4], bfr[4];
    #pragma unroll
    for (int m = 0; m < 4; m++)
      af[m] = *(const bf16x8*)((const char*)As + (wm + m*16 + lr)*64 + lkb);
    #pragma unroll
    for (int n = 0; n < 4; n++)
      bfr[n] = *(const bf16x8*)((const char*)Bs + (wn + n*16 + lr)*64 + lkb);
    #pragma unroll
    for (int m = 0; m < 4; m++)
      #pragma unroll
      for (int n = 0; n < 4; n++)
        acc[m][n] = mfma16(af[m], bfr[n], acc[m][n]);
    __syncthreads();
  }

  const int cr = (lane >> 4) * 4;
  #pragma unroll
  for (int m = 0; m < 4; m++)
    #pragma unroll
    for (int n = 0; n < 4; n++)
      #pragma unroll
      for (int j = 0; j < 4; j++){
        size_t row = (size_t)(m0 + wm + m*16 + cr + j);
        size_t col = (size_t)(n0 + wn + n*16 + lr);
        if (OUTBF) ((u16*)Cp)[row*(size_t)N + col] = f2bf(acc[m][n][j]);
        else       ((float*)Cp)[row*(size_t)N + col] = acc[m][n][j];
      }
}

// ---------------- flash attention (causal), bf16 in/out ----------------
// 1024 blocks, 4/CU co-resident. qtb chosen so each stride-256 co-resident
// set {g, g+4, g+8, g+12} has equal total work (sum of qtb = 30):
//   perm = {15,13,11,9, 0,2,4,6, 14,12,10,8, 1,3,5,7}
// 256 thr = 4 waves; wave w owns q rows {m*64 + w*16 + [0,16)} for m=0,1.
__global__ __launch_bounds__(256, 2) void attn_fwd(const u16* __restrict__ qkv,
                                                   u16* __restrict__ y){
  __shared__ u16 Kl[64*72];      // K tile [k][d], row stride 72 (odd*16B)
  __shared__ u16 Vt[64*72];      // V^T tile [d][k], row stride 72
  __shared__ u16 Pl[4][32*72];   // per-wave P [q32][k64], row stride 72
  const int bid = blockIdx.x;
  const int g = bid >> 6;
  const int g2 = g & 3, gc = g >> 2;
  int qtb;
  if      (gc == 0) qtb = 15 - 2*g2;
  else if (gc == 1) qtb = 2*g2;
  else if (gc == 2) qtb = 14 - 2*g2;
  else              qtb = 1 + 2*g2;
  const int h = bid & 15, b = (bid >> 4) & 3;
  const int tid = threadIdx.x, lane = tid & 63, w = tid >> 6;
  const int lr = lane & 15, lg = lane >> 4;
  const size_t base = (size_t)b * TT * C3;
  const int q0 = qtb * 128;

  // Q fragments (A-operand): row = lr, d = ks*32 + lg*8 + j
  bf16x8 qf[2][2];
  #pragma unroll
  for (int m = 0; m < 2; m++){
    const u16* qp = qkv + base + (size_t)(q0 + m*64 + w*16 + lr) * C3 + h*HD;
    qf[m][0] = *(const bf16x8*)(qp + lg*8);
    qf[m][1] = *(const bf16x8*)(qp + 32 + lg*8);
  }

  // staging maps: K coalesced (row = tid>>3), V k-major lanes (row = tid&31)
  const int rK = tid >> 3, cK = tid & 7;
  const int rV = tid & 31, cV = tid >> 5;
  const u16* gK = qkv + base + (size_t)rK * C3 + CC   + h*HD + cK*8;
  const u16* gV = qkv + base + (size_t)rV * C3 + 2*CC + h*HD + cV*8;

  u16x8 kreg[2], vreg[2];
  kreg[0] = *(const u16x8*)(gK);
  kreg[1] = *(const u16x8*)(gK + (size_t)32*C3);
  vreg[0] = *(const u16x8*)(gV);
  vreg[1] = *(const u16x8*)(gV + (size_t)32*C3);

  f32x4 o[2][4] = {};
  float mj[2][4], lj[2][4];
  #pragma unroll
  for (int m = 0; m < 2; m++)
    #pragma unroll
    for (int j = 0; j < 4; j++){ mj[m][j] = -1e30f; lj[m][j] = 0.f; }
  const float SC = 0.18033688011112042f;   // (1/8) * log2(e)

  const int ktmax = 2*qtb + 1;
  for (int kt = 0; kt <= ktmax; kt++){
    __syncthreads();   // previous tile's LDS reads complete
    *(u16x8*)&Kl[rK*72 + cK*8] = kreg[0];
    *(u16x8*)&Kl[(rK+32)*72 + cK*8] = kreg[1];
    #pragma unroll
    for (int i = 0; i < 2; i++)
      #pragma unroll
      for (int e = 0; e < 8; e++)
        Vt[(cV*8+e)*72 + i*32 + rV] = vreg[i][e];
    __syncthreads();

    // prefetch next tile into regs (hides under compute)
    if (kt < ktmax){
      const u16* gk2 = gK + (size_t)(kt+1)*64*C3;
      const u16* gv2 = gV + (size_t)(kt+1)*64*C3;
      kreg[0] = *(const u16x8*)(gk2);
      kreg[1] = *(const u16x8*)(gk2 + (size_t)32*C3);
      vreg[0] = *(const u16x8*)(gv2);
      vreg[1] = *(const u16x8*)(gv2 + (size_t)32*C3);
    }

    // S = Q K^T : s[m][n], shared B-frags across m
    f32x4 s[2][4] = {};
    __builtin_amdgcn_s_setprio(1);
    #pragma unroll
    for (int n = 0; n < 4; n++){
      bf16x8 kb0 = *(const bf16x8*)&Kl[(n*16+lr)*72 + lg*8];
      bf16x8 kb1 = *(const bf16x8*)&Kl[(n*16+lr)*72 + 32 + lg*8];
      #pragma unroll
      for (int m = 0; m < 2; m++){
        s[m][n] = mfma16(qf[m][0], kb0, s[m][n]);
        s[m][n] = mfma16(qf[m][1], kb1, s[m][n]);
      }
    }
    __builtin_amdgcn_s_setprio(0);

    const bool domask = (kt >= 2*qtb);
    #pragma unroll
    for (int m = 0; m < 2; m++){
      #pragma unroll
      for (int j = 0; j < 4; j++){
        float t0 = s[m][0][j]*SC, t1 = s[m][1][j]*SC,
              t2 = s[m][2][j]*SC, t3 = s[m][3][j]*SC;
        if (domask){
          int q = q0 + m*64 + w*16 + lg*4 + j;
          int kb = kt*64 + lr;
          if (kb      > q) t0 = -1e30f;
          if (kb + 16 > q) t1 = -1e30f;
          if (kb + 32 > q) t2 = -1e30f;
          if (kb + 48 > q) t3 = -1e30f;
        }
        float tm = fmaxf(fmaxf(t0, t1), fmaxf(t2, t3));
        #pragma unroll
        for (int d = 1; d < 16; d <<= 1) tm = fmaxf(tm, __shfl_xor(tm, d, 64));
        float mo = mj[m][j];
        float mn;
        if (__all(tm <= mo)){          // T13 defer-max: no rescale needed
          mn = mo;
        } else {
          mn = fmaxf(mo, tm);
          float al = __builtin_amdgcn_exp2f(mo - mn);
          mj[m][j] = mn;
          lj[m][j] *= al;
          o[m][0][j] *= al; o[m][1][j] *= al; o[m][2][j] *= al; o[m][3][j] *= al;
        }
        float p0 = __builtin_amdgcn_exp2f(t0 - mn);
        float p1 = __builtin_amdgcn_exp2f(t1 - mn);
        float p2 = __builtin_amdgcn_exp2f(t2 - mn);
        float p3 = __builtin_amdgcn_exp2f(t3 - mn);
        float ps = (p0 + p1) + (p2 + p3);
        #pragma unroll
        for (int d = 1; d < 16; d <<= 1) ps += __shfl_xor(ps, d, 64);
        lj[m][j] += ps;
        int prow = m*16 + lg*4 + j;
        Pl[w][prow*72 +      lr] = f2bf(p0);
        Pl[w][prow*72 + 16 + lr] = f2bf(p1);
        Pl[w][prow*72 + 32 + lr] = f2bf(p2);
        Pl[w][prow*72 + 48 + lr] = f2bf(p3);
      }
    }
    asm volatile("s_waitcnt lgkmcnt(0)" ::: "memory");

    // O += P V
    __builtin_amdgcn_s_setprio(1);
    #pragma unroll
    for (int ks = 0; ks < 2; ks++){
      bf16x8 pa0 = *(const bf16x8*)&Pl[w][(lr     )*72 + ks*32 + lg*8];
      bf16x8 pa1 = *(const bf16x8*)&Pl[w][(16 + lr)*72 + ks*32 + lg*8];
      #pragma unroll
      for (int n = 0; n < 4; n++){
        bf16x8 vb = *(const bf16x8*)&Vt[(n*16+lr)*72 + ks*32 + lg*8];
        o[0][n] = mfma16(pa0, vb, o[0][n]);
        o[1][n] = mfma16(pa1, vb, o[1][n]);
      }
    }
    __builtin_amdgcn_s_setprio(0);
  }

  // normalize + write y (bf16)
  #pragma unroll
  for (int m = 0; m < 2; m++)
    #pragma unroll
    for (int j = 0; j < 4; j++){
      float inv = 1.0f / lj[m][j];
      size_t row = (size_t)b*TT + q0 + m*64 + w*16 + lg*4 + j;
      #pragma unroll
      for (int n = 0; n < 4; n++)
        y[row*CC + h*HD + n*16 + lr] = f2bf(o[m][n][j] * inv);
    }
}

// ---------------- launch ----------------
extern "C" void kernel_launch(void* const* d_in, const int* in_sizes, int n_in,
                              void* d_out, int out_size, void* d_ws, size_t ws_size,
                              hipStream_t stream){
  const float* x     = (const float*)d_in[0];
  const float* w_in  = (const float*)d_in[1];
  const float* w_out = (const float*)d_in[2];
  float* out = (float*)d_out;

  u16* xb   = (u16*)d_ws;                  // 8192*1024  (reused as y after GEMM1)
  u16* wib  = xb  + (size_t)MM * CC;       // 3072*1024
  u16* wob  = wib + (size_t)C3 * CC;       // 1024*1024
  u16* qkvb = wob + (size_t)CC * CC;       // 8192*3072
  u16* yb   = xb;                          // x is dead after GEMM1

  auto nblk = [](int n8){ int g = (n8 + 255) / 256; return g > 2048 ? 2048 : g; };
  cvt_bf16<<<nblk(MM*CC/8), 256, 0, stream>>>(x,     xb,  MM*CC/8);
  cvt_bf16<<<nblk(C3*CC/8), 256, 0, stream>>>(w_in,  wib, C3*CC/8);
  cvt_bf16<<<nblk(CC*CC/8), 256, 0, stream>>>(w_out, wob, CC*CC/8);

  gemm_bt<1><<<dim3(C3/128, MM/128), 256, 0, stream>>>(xb, wib, (void*)qkvb, MM, C3, CC);
  attn_fwd<<<1024, 256, 0, stream>>>(qkvb, yb);
  gemm_bt<0><<<dim3(CC/128, MM/128), 256, 0, stream>>>(yb, wob, (void*)out, MM, CC, CC);
}

// Round 5
// 219.581 us; speedup vs baseline: 1.4075x; 1.1337x over previous
//
#include <hip/hip_runtime.h>
#include <stdint.h>

#define BB 4
#define TT 2048
#define CC 1024
#define HH 16
#define HD 64
#define C3 3072
#define MM (BB*TT)   // 8192 rows

typedef __bf16 bf16_t;
typedef bf16_t bf16x8 __attribute__((ext_vector_type(8)));
typedef float f32x4 __attribute__((ext_vector_type(4)));
typedef unsigned short u16;
typedef u16 u16x8 __attribute__((ext_vector_type(8)));
typedef u16 u16x4 __attribute__((ext_vector_type(4)));
typedef uint32_t u32;

// f32 -> bf16 round-to-nearest-even
static __device__ __forceinline__ u16 f2bf(float f){
  u32 u = __builtin_bit_cast(u32, f);
  u32 r = (u + 0x7fffu + ((u >> 16) & 1u)) >> 16;
  return (u16)r;
}

static __device__ __forceinline__ f32x4 mfma16(bf16x8 a, bf16x8 b, f32x4 c){
  return __builtin_amdgcn_mfma_f32_16x16x32_bf16(a, b, c, 0, 0, 0);
}

typedef __attribute__((address_space(1))) void* gas_t;
typedef __attribute__((address_space(3))) void* las_t;
static __device__ __forceinline__ void gload16(const void* g, void* l){
  __builtin_amdgcn_global_load_lds((gas_t)g, (las_t)l, 16, 0, 0);
}

// ---------------- fp32 -> bf16 conversion (vectorized) ----------------
__global__ __launch_bounds__(256) void cvt_bf16(const float* __restrict__ in,
                                                u16* __restrict__ out, int n8){
  int stride = gridDim.x * blockDim.x;
  for (int i = blockIdx.x * blockDim.x + threadIdx.x; i < n8; i += stride){
    const float4* p = (const float4*)in + (size_t)i * 2;
    float4 a = p[0], b = p[1];
    u16x8 o;
    o[0]=f2bf(a.x); o[1]=f2bf(a.y); o[2]=f2bf(a.z); o[3]=f2bf(a.w);
    o[4]=f2bf(b.x); o[5]=f2bf(b.y); o[6]=f2bf(b.z); o[7]=f2bf(b.w);
    *((u16x8*)out + i) = o;
  }
}

// ---------------- bt-GEMM: C[M,N] = A[M,K] * B[N,K]^T  (m97 structure) --------
template<int OUTBF>
__global__ __launch_bounds__(256) void gemm_bt(const u16* __restrict__ A,
                                               const u16* __restrict__ Bm,
                                               void* __restrict__ Cp,
                                               int M, int N, int K){
  __shared__ u16 As[128*32];
  __shared__ u16 Bs[128*32];
  const int tid  = threadIdx.x;
  const int lane = tid & 63;
  const int w    = tid >> 6;
  const int m0   = blockIdx.y * 128;
  const int n0   = blockIdx.x * 128;
  const int wm   = (w >> 1) * 64;
  const int wn   = (w & 1) * 64;
  const int lr   = lane & 15;
  const int lkb  = (lane >> 4) * 16;

  f32x4 acc[4][4] = {};

  const int r0 = w*32 + (lane >> 2);
  const int c8 = (lane & 3) * 8;
  const u16* gA = A  + (size_t)(m0 + r0) * K + c8;
  const u16* gB = Bm + (size_t)(n0 + r0) * K + c8;
  char* lA = (char*)As + w*2048 + lane*16;
  char* lB = (char*)Bs + w*2048 + lane*16;

  for (int k0 = 0; k0 < K; k0 += 32){
    gload16(gA + k0,                 lA);
    gload16(gA + (size_t)16*K + k0,  lA + 1024);
    gload16(gB + k0,                 lB);
    gload16(gB + (size_t)16*K + k0,  lB + 1024);
    __syncthreads();
    bf16x8 af[4], bfr[4];
    #pragma unroll
    for (int m = 0; m < 4; m++)
      af[m] = *(const bf16x8*)((const char*)As + (wm + m*16 + lr)*64 + lkb);
    #pragma unroll
    for (int n = 0; n < 4; n++)
      bfr[n] = *(const bf16x8*)((const char*)Bs + (wn + n*16 + lr)*64 + lkb);
    #pragma unroll
    for (int m = 0; m < 4; m++)
      #pragma unroll
      for (int n = 0; n < 4; n++)
        acc[m][n] = mfma16(af[m], bfr[n], acc[m][n]);
    __syncthreads();
  }

  const int cr = (lane >> 4) * 4;
  #pragma unroll
  for (int m = 0; m < 4; m++)
    #pragma unroll
    for (int n = 0; n < 4; n++)
      #pragma unroll
      for (int j = 0; j < 4; j++){
        size_t row = (size_t)(m0 + wm + m*16 + cr + j);
        size_t col = (size_t)(n0 + wn + n*16 + lr);
        if (OUTBF) ((u16*)Cp)[row*(size_t)N + col] = f2bf(acc[m][n][j]);
        else       ((float*)Cp)[row*(size_t)N + col] = acc[m][n][j];
      }
}

// ---------------- flash attention (causal), bf16 in/out ----------------
// Block = q-tile PAIR (t, 31-t): m=0 group handles tile t, m=1 handles 31-t.
// kt loop runs 0..31-t; m=0 active only for kt<=t  ->  constant 33 half-tile
// units of work per block (perfect balance). t in low bid bits for L2 reuse.
// Swapped QK^T: S = mfma(K,Q) -> lane holds q=lr, k = n*16+lg*4+j
// (in-lane row reduce + 2 shfl_xor; alpha/inv broadcast via 4 shfl).
__global__ __launch_bounds__(256, 2) void attn_fwd(const u16* __restrict__ qkv,
                                                   u16* __restrict__ y){
  __shared__ u16 Kl[64*72];      // K tile [k][d], row stride 72 (odd*16B)
  __shared__ u16 Vt[64*72];      // V^T tile [d][k], row stride 72
  __shared__ u16 Pl[4][32*72];   // per-wave P [q32][k64], row stride 72
  const int bid = blockIdx.x;
  const int tq = bid & 15;
  const int h = (bid >> 4) & 15, b = bid >> 8;
  const int tid = threadIdx.x, lane = tid & 63, w = tid >> 6;
  const int lr = lane & 15, lg = lane >> 4;
  const size_t base = (size_t)b * TT * C3;
  const int qA = tq*64 + w*16;          // m=0 wave q-base
  const int qB = (31-tq)*64 + w*16;     // m=1 wave q-base

  // Q fragments (B-operand for swapped QK): row = lr, d = ks*32 + lg*8
  bf16x8 qf[2][2];
  {
    const u16* qp0 = qkv + base + (size_t)(qA + lr) * C3 + h*HD;
    qf[0][0] = *(const bf16x8*)(qp0 + lg*8);
    qf[0][1] = *(const bf16x8*)(qp0 + 32 + lg*8);
    const u16* qp1 = qkv + base + (size_t)(qB + lr) * C3 + h*HD;
    qf[1][0] = *(const bf16x8*)(qp1 + lg*8);
    qf[1][1] = *(const bf16x8*)(qp1 + 32 + lg*8);
  }

  // staging maps: K coalesced (row = tid>>3), V k-major lanes (row = tid&31)
  const int rK = tid >> 3, cK = tid & 7;
  const int rV = tid & 31, cV = tid >> 5;
  const u16* gK = qkv + base + (size_t)rK * C3 + CC   + h*HD + cK*8;
  const u16* gV = qkv + base + (size_t)rV * C3 + 2*CC + h*HD + cV*8;

  u16x8 kreg[2], vreg[2];
  kreg[0] = *(const u16x8*)(gK);
  kreg[1] = *(const u16x8*)(gK + (size_t)32*C3);
  vreg[0] = *(const u16x8*)(gV);
  vreg[1] = *(const u16x8*)(gV + (size_t)32*C3);

  f32x4 o[2][4] = {};
  float mj[2] = {-1e30f, -1e30f};
  float lj[2] = {0.f, 0.f};
  const float SC = 0.18033688011112042f;   // (1/8) * log2(e)

  const int ktmax = 31 - tq;
  for (int kt = 0; kt <= ktmax; kt++){
    __syncthreads();   // previous tile's LDS reads complete
    *(u16x8*)&Kl[rK*72 + cK*8] = kreg[0];
    *(u16x8*)&Kl[(rK+32)*72 + cK*8] = kreg[1];
    #pragma unroll
    for (int i = 0; i < 2; i++)
      #pragma unroll
      for (int e = 0; e < 8; e++)
        Vt[(cV*8+e)*72 + i*32 + rV] = vreg[i][e];
    __syncthreads();

    // prefetch next tile into regs (hides under compute)
    if (kt < ktmax){
      const u16* gk2 = gK + (size_t)(kt+1)*64*C3;
      const u16* gv2 = gV + (size_t)(kt+1)*64*C3;
      kreg[0] = *(const u16x8*)(gk2);
      kreg[1] = *(const u16x8*)(gk2 + (size_t)32*C3);
      vreg[0] = *(const u16x8*)(gv2);
      vreg[1] = *(const u16x8*)(gv2 + (size_t)32*C3);
    }

    const bool m0act = (kt <= tq);

    // S^T = K Q^T : lane holds q=lr, k = n*16 + lg*4 + j
    f32x4 s[2][4] = {};
    __builtin_amdgcn_s_setprio(1);
    #pragma unroll
    for (int n = 0; n < 4; n++){
      bf16x8 kb0 = *(const bf16x8*)&Kl[(n*16+lr)*72 + lg*8];
      bf16x8 kb1 = *(const bf16x8*)&Kl[(n*16+lr)*72 + 32 + lg*8];
      if (m0act){
        s[0][n] = mfma16(kb0, qf[0][0], s[0][n]);
        s[0][n] = mfma16(kb1, qf[0][1], s[0][n]);
      }
      s[1][n] = mfma16(kb0, qf[1][0], s[1][n]);
      s[1][n] = mfma16(kb1, qf[1][1], s[1][n]);
    }
    __builtin_amdgcn_s_setprio(0);

    // online softmax, in-lane over 16 k-values, 2 shfl_xor across lg groups
    #pragma unroll
    for (int m = 0; m < 2; m++){
      if (m == 0 && !m0act) continue;
      const int qrow = (m ? qB : qA) + lr;
      const bool dm = (kt == (m ? ktmax : tq));   // diagonal tile for this m
      float t[4][4];
      #pragma unroll
      for (int n = 0; n < 4; n++)
        #pragma unroll
        for (int j = 0; j < 4; j++){
          float v = s[m][n][j] * SC;
          if (dm && (kt*64 + n*16 + lg*4 + j > qrow)) v = -1e30f;
          t[n][j] = v;
        }
      float tm = t[0][0];
      #pragma unroll
      for (int n = 0; n < 4; n++)
        #pragma unroll
        for (int j = 0; j < 4; j++) tm = fmaxf(tm, t[n][j]);
      tm = fmaxf(tm, __shfl_xor(tm, 16, 64));
      tm = fmaxf(tm, __shfl_xor(tm, 32, 64));
      float mo = mj[m];
      if (!__all(tm <= mo)){         // T13 defer-max (strict)
        float mn = fmaxf(mo, tm);
        float al = __builtin_amdgcn_exp2f(mo - mn);
        mj[m] = mn;
        lj[m] *= al;
        float a0 = __shfl(al, lg*4+0, 16);
        float a1 = __shfl(al, lg*4+1, 16);
        float a2 = __shfl(al, lg*4+2, 16);
        float a3 = __shfl(al, lg*4+3, 16);
        #pragma unroll
        for (int n = 0; n < 4; n++){
          o[m][n][0] *= a0; o[m][n][1] *= a1;
          o[m][n][2] *= a2; o[m][n][3] *= a3;
        }
      }
      float mm = mj[m];
      float ps = 0.f;
      #pragma unroll
      for (int n = 0; n < 4; n++){
        float p0 = __builtin_amdgcn_exp2f(t[n][0] - mm);
        float p1 = __builtin_amdgcn_exp2f(t[n][1] - mm);
        float p2 = __builtin_amdgcn_exp2f(t[n][2] - mm);
        float p3 = __builtin_amdgcn_exp2f(t[n][3] - mm);
        ps += (p0 + p1) + (p2 + p3);
        u16x4 pk;
        pk[0]=f2bf(p0); pk[1]=f2bf(p1); pk[2]=f2bf(p2); pk[3]=f2bf(p3);
        *(u16x4*)&Pl[w][(m*16+lr)*72 + n*16 + lg*4] = pk;
      }
      ps += __shfl_xor(ps, 16, 64);
      ps += __shfl_xor(ps, 32, 64);
      lj[m] += ps;
    }
    asm volatile("s_waitcnt lgkmcnt(0)" ::: "memory");

    // O += P V
    __builtin_amdgcn_s_setprio(1);
    #pragma unroll
    for (int ks = 0; ks < 2; ks++){
      bf16x8 pa0 = *(const bf16x8*)&Pl[w][(lr     )*72 + ks*32 + lg*8];
      bf16x8 pa1 = *(const bf16x8*)&Pl[w][(16 + lr)*72 + ks*32 + lg*8];
      #pragma unroll
      for (int n = 0; n < 4; n++){
        bf16x8 vb = *(const bf16x8*)&Vt[(n*16+lr)*72 + ks*32 + lg*8];
        if (m0act) o[0][n] = mfma16(pa0, vb, o[0][n]);
        o[1][n] = mfma16(pa1, vb, o[1][n]);
      }
    }
    __builtin_amdgcn_s_setprio(0);
  }

  // normalize + write y (bf16); 1/l transposed to o's row layout via shfl
  #pragma unroll
  for (int m = 0; m < 2; m++){
    float inv = 1.0f / lj[m];
    float i0 = __shfl(inv, lg*4+0, 16);
    float i1 = __shfl(inv, lg*4+1, 16);
    float i2 = __shfl(inv, lg*4+2, 16);
    float i3 = __shfl(inv, lg*4+3, 16);
    const int qb = (m ? qB : qA);
    #pragma unroll
    for (int j = 0; j < 4; j++){
      float ij = (j==0) ? i0 : (j==1) ? i1 : (j==2) ? i2 : i3;
      size_t row = (size_t)b*TT + qb + lg*4 + j;
      #pragma unroll
      for (int n = 0; n < 4; n++)
        y[row*CC + h*HD + n*16 + lr] = f2bf(o[m][n][j] * ij);
    }
  }
}

// ---------------- launch ----------------
extern "C" void kernel_launch(void* const* d_in, const int* in_sizes, int n_in,
                              void* d_out, int out_size, void* d_ws, size_t ws_size,
                              hipStream_t stream){
  const float* x     = (const float*)d_in[0];
  const float* w_in  = (const float*)d_in[1];
  const float* w_out = (const float*)d_in[2];
  float* out = (float*)d_out;

  u16* xb   = (u16*)d_ws;                  // 8192*1024  (reused as y after GEMM1)
  u16* wib  = xb  + (size_t)MM * CC;       // 3072*1024
  u16* wob  = wib + (size_t)C3 * CC;       // 1024*1024
  u16* qkvb = wob + (size_t)CC * CC;       // 8192*3072
  u16* yb   = xb;                          // x is dead after GEMM1

  auto nblk = [](int n8){ int g = (n8 + 255) / 256; return g > 2048 ? 2048 : g; };
  cvt_bf16<<<nblk(MM*CC/8), 256, 0, stream>>>(x,     xb,  MM*CC/8);
  cvt_bf16<<<nblk(C3*CC/8), 256, 0, stream>>>(w_in,  wib, C3*CC/8);
  cvt_bf16<<<nblk(CC*CC/8), 256, 0, stream>>>(w_out, wob, CC*CC/8);

  gemm_bt<1><<<dim3(C3/128, MM/128), 256, 0, stream>>>(xb, wib, (void*)qkvb, MM, C3, CC);
  attn_fwd<<<1024, 256, 0, stream>>>(qkvb, yb);
  gemm_bt<0><<<dim3(CC/128, MM/128), 256, 0, stream>>>(yb, wob, (void*)out, MM, CC, CC);
}

// Round 6
// 197.329 us; speedup vs baseline: 1.5662x; 1.1128x over previous
//
#include <hip/hip_runtime.h>
#include <stdint.h>

#define BB 4
#define TT 2048
#define CC 1024
#define HH 16
#define HD 64
#define C3 3072
#define MM (BB*TT)   // 8192 rows

typedef __bf16 bf16_t;
typedef bf16_t bf16x8 __attribute__((ext_vector_type(8)));
typedef float f32x4 __attribute__((ext_vector_type(4)));
typedef unsigned short u16;
typedef u16 u16x8 __attribute__((ext_vector_type(8)));
typedef uint32_t u32;

// f32 -> bf16 round-to-nearest-even
static __device__ __forceinline__ u16 f2bf(float f){
  u32 u = __builtin_bit_cast(u32, f);
  u32 r = (u + 0x7fffu + ((u >> 16) & 1u)) >> 16;
  return (u16)r;
}

static __device__ __forceinline__ f32x4 mfma16(bf16x8 a, bf16x8 b, f32x4 c){
  return __builtin_amdgcn_mfma_f32_16x16x32_bf16(a, b, c, 0, 0, 0);
}

typedef __attribute__((address_space(1))) void* gas_t;
typedef __attribute__((address_space(3))) void* las_t;
static __device__ __forceinline__ void gload16(const void* g, void* l){
  __builtin_amdgcn_global_load_lds((gas_t)g, (las_t)l, 16, 0, 0);
}

// ---------------- fp32 -> bf16 conversion (vectorized) ----------------
__global__ __launch_bounds__(256) void cvt_bf16(const float* __restrict__ in,
                                                u16* __restrict__ out, int n8){
  int stride = gridDim.x * blockDim.x;
  for (int i = blockIdx.x * blockDim.x + threadIdx.x; i < n8; i += stride){
    const float4* p = (const float4*)in + (size_t)i * 2;
    float4 a = p[0], b = p[1];
    u16x8 o;
    o[0]=f2bf(a.x); o[1]=f2bf(a.y); o[2]=f2bf(a.z); o[3]=f2bf(a.w);
    o[4]=f2bf(b.x); o[5]=f2bf(b.y); o[6]=f2bf(b.z); o[7]=f2bf(b.w);
    *((u16x8*)out + i) = o;
  }
}

// ---------------- bt-GEMM: C[M,N] = A[M,K] * B[N,K]^T  (m97 structure) --------
template<int OUTBF>
__global__ __launch_bounds__(256) void gemm_bt(const u16* __restrict__ A,
                                               const u16* __restrict__ Bm,
                                               void* __restrict__ Cp,
                                               int M, int N, int K){
  __shared__ u16 As[128*32];
  __shared__ u16 Bs[128*32];
  const int tid  = threadIdx.x;
  const int lane = tid & 63;
  const int w    = tid >> 6;
  const int m0   = blockIdx.y * 128;
  const int n0   = blockIdx.x * 128;
  const int wm   = (w >> 1) * 64;
  const int wn   = (w & 1) * 64;
  const int lr   = lane & 15;
  const int lkb  = (lane >> 4) * 16;

  f32x4 acc[4][4] = {};

  const int r0 = w*32 + (lane >> 2);
  const int c8 = (lane & 3) * 8;
  const u16* gA = A  + (size_t)(m0 + r0) * K + c8;
  const u16* gB = Bm + (size_t)(n0 + r0) * K + c8;
  char* lA = (char*)As + w*2048 + lane*16;
  char* lB = (char*)Bs + w*2048 + lane*16;

  for (int k0 = 0; k0 < K; k0 += 32){
    gload16(gA + k0,                 lA);
    gload16(gA + (size_t)16*K + k0,  lA + 1024);
    gload16(gB + k0,                 lB);
    gload16(gB + (size_t)16*K + k0,  lB + 1024);
    __syncthreads();
    bf16x8 af[4], bfr[4];
    #pragma unroll
    for (int m = 0; m < 4; m++)
      af[m] = *(const bf16x8*)((const char*)As + (wm + m*16 + lr)*64 + lkb);
    #pragma unroll
    for (int n = 0; n < 4; n++)
      bfr[n] = *(const bf16x8*)((const char*)Bs + (wn + n*16 + lr)*64 + lkb);
    #pragma unroll
    for (int m = 0; m < 4; m++)
      #pragma unroll
      for (int n = 0; n < 4; n++)
        acc[m][n] = mfma16(af[m], bfr[n], acc[m][n]);
    __syncthreads();
  }

  const int cr = (lane >> 4) * 4;
  #pragma unroll
  for (int m = 0; m < 4; m++)
    #pragma unroll
    for (int n = 0; n < 4; n++)
      #pragma unroll
      for (int j = 0; j < 4; j++){
        size_t row = (size_t)(m0 + wm + m*16 + cr + j);
        size_t col = (size_t)(n0 + wn + n*16 + lr);
        if (OUTBF) ((u16*)Cp)[row*(size_t)N + col] = f2bf(acc[m][n][j]);
        else       ((float*)Cp)[row*(size_t)N + col] = acc[m][n][j];
      }
}

// ---------------- flash attention (causal), bf16 in/out ----------------
// Block = q-tile PAIR (tq, 31-tq), constant work. bid = h + 16b + 64tq so
// same-(b,h) blocks are stride-64 (same XCD -> one L2 copy of K/V).
// Swapped QK^T with PERMUTED K-rows: A-frag row i of chunk n = K-row
//   rho(n,i) = 32(n>>1) + 8(i>>2) + 4(n&1) + (i&3)
// so lane (lr,lg) gets S[q=lr][k=32(n>>1)+8lg+4(n&1)+j]; its P-quads
// concatenate natively into the PV A-operand (k=32ks+8lg+j') -> no P LDS.
// Kl XOR-swizzle: col ^= ((row>>3)&1)<<5 (u16) on writes & kb reads.
__global__ __launch_bounds__(256, 2) void attn_fwd(const u16* __restrict__ qkv,
                                                   u16* __restrict__ y){
  __shared__ u16 Kl[64*72];      // K tile [k][d], row stride 72, XOR-swizzled
  __shared__ u16 Vt[64*72];      // V^T tile [d][k], row stride 72
  const int bid = blockIdx.x;
  const int tq = bid >> 6;
  const int h = bid & 15, b = (bid >> 4) & 3;
  const int tid = threadIdx.x, lane = tid & 63, w = tid >> 6;
  const int lr = lane & 15, lg = lane >> 4;
  const size_t base = (size_t)b * TT * C3;
  const int qA = tq*64 + w*16;          // m=0 wave q-base
  const int qB = (31-tq)*64 + w*16;     // m=1 wave q-base

  // Q fragments (B-operand): row = lr, d = ks*32 + lg*8
  bf16x8 qf[2][2];
  {
    const u16* qp0 = qkv + base + (size_t)(qA + lr) * C3 + h*HD;
    qf[0][0] = *(const bf16x8*)(qp0 + lg*8);
    qf[0][1] = *(const bf16x8*)(qp0 + 32 + lg*8);
    const u16* qp1 = qkv + base + (size_t)(qB + lr) * C3 + h*HD;
    qf[1][0] = *(const bf16x8*)(qp1 + lg*8);
    qf[1][1] = *(const bf16x8*)(qp1 + 32 + lg*8);
  }

  // staging maps: K coalesced (row = tid>>3), V k-major lanes (row = tid&31)
  const int rK = tid >> 3, cK = tid & 7;
  const int rV = tid & 31, cV = tid >> 5;
  const u16* gK = qkv + base + (size_t)rK * C3 + CC   + h*HD + cK*8;
  const u16* gV = qkv + base + (size_t)rV * C3 + 2*CC + h*HD + cV*8;

  // swizzled K write indices (key = (row>>3)&1, same for row and row+32)
  const int kkey = ((rK >> 3) & 1) << 5;
  const int kw0 = rK*72 + ((cK*8) ^ kkey);
  const int kw1 = (rK+32)*72 + ((cK*8) ^ kkey);

  // kb read: row rho(n,lr) -> key depends only on (lr>>2)&1
  const int rdx = ((lr >> 2) & 1) << 5;
  const int rbase = 8*(lr >> 2) + (lr & 3);     // row part from lr

  u16x8 kreg[2], vreg[2];
  kreg[0] = *(const u16x8*)(gK);
  kreg[1] = *(const u16x8*)(gK + (size_t)32*C3);
  vreg[0] = *(const u16x8*)(gV);
  vreg[1] = *(const u16x8*)(gV + (size_t)32*C3);

  f32x4 o[2][4] = {};
  float mj[2] = {-1e30f, -1e30f};
  float lj[2] = {0.f, 0.f};
  const float SC = 0.18033688011112042f;   // (1/8) * log2(e)

  const int ktmax = 31 - tq;
  for (int kt = 0; kt <= ktmax; kt++){
    __syncthreads();   // previous tile's LDS reads complete
    *(u16x8*)&Kl[kw0] = kreg[0];
    *(u16x8*)&Kl[kw1] = kreg[1];
    #pragma unroll
    for (int i = 0; i < 2; i++)
      #pragma unroll
      for (int e = 0; e < 8; e++)
        Vt[(cV*8+e)*72 + i*32 + rV] = vreg[i][e];
    __syncthreads();

    // prefetch next tile into regs (hides under compute)
    if (kt < ktmax){
      const u16* gk2 = gK + (size_t)(kt+1)*64*C3;
      const u16* gv2 = gV + (size_t)(kt+1)*64*C3;
      kreg[0] = *(const u16x8*)(gk2);
      kreg[1] = *(const u16x8*)(gk2 + (size_t)32*C3);
      vreg[0] = *(const u16x8*)(gv2);
      vreg[1] = *(const u16x8*)(gv2 + (size_t)32*C3);
    }

    const bool m0act = (kt <= tq);

    // S^T via permuted K-rows: lane holds S[q=lr][k=32(n>>1)+8lg+4(n&1)+j]
    f32x4 s[2][4] = {};
    __builtin_amdgcn_s_setprio(1);
    #pragma unroll
    for (int n = 0; n < 4; n++){
      const int rho = 32*(n>>1) + 4*(n&1) + rbase;
      bf16x8 kb0 = *(const bf16x8*)&Kl[rho*72 + ((     lg*8) ^ rdx)];
      bf16x8 kb1 = *(const bf16x8*)&Kl[rho*72 + ((32 + lg*8) ^ rdx)];
      if (m0act){
        s[0][n] = mfma16(kb0, qf[0][0], s[0][n]);
        s[0][n] = mfma16(kb1, qf[0][1], s[0][n]);
      }
      s[1][n] = mfma16(kb0, qf[1][0], s[1][n]);
      s[1][n] = mfma16(kb1, qf[1][1], s[1][n]);
    }
    __builtin_amdgcn_s_setprio(0);

    // online softmax (in-lane 16 + 2 shfl_xor) and native P-pack
    bf16x8 paA[2], paB[2];
    #pragma unroll
    for (int m = 0; m < 2; m++){
      if (m == 0 && !m0act) continue;
      const int qrow = (m ? qB : qA) + lr;
      const bool dm = (kt == (m ? ktmax : tq));   // diagonal tile for this m
      float t[4][4];
      #pragma unroll
      for (int n = 0; n < 4; n++)
        #pragma unroll
        for (int j = 0; j < 4; j++){
          float v = s[m][n][j] * SC;
          if (dm && (kt*64 + 32*(n>>1) + 8*lg + 4*(n&1) + j > qrow)) v = -1e30f;
          t[n][j] = v;
        }
      float tm = t[0][0];
      #pragma unroll
      for (int n = 0; n < 4; n++)
        #pragma unroll
        for (int j = 0; j < 4; j++) tm = fmaxf(tm, t[n][j]);
      tm = fmaxf(tm, __shfl_xor(tm, 16, 64));
      tm = fmaxf(tm, __shfl_xor(tm, 32, 64));
      float mo = mj[m];
      if (!__all(tm <= mo)){         // T13 defer-max (strict)
        float mn = fmaxf(mo, tm);
        float al = __builtin_amdgcn_exp2f(mo - mn);
        mj[m] = mn;
        lj[m] *= al;
        float a0 = __shfl(al, lg*4+0, 16);
        float a1 = __shfl(al, lg*4+1, 16);
        float a2 = __shfl(al, lg*4+2, 16);
        float a3 = __shfl(al, lg*4+3, 16);
        #pragma unroll
        for (int n = 0; n < 4; n++){
          o[m][n][0] *= a0; o[m][n][1] *= a1;
          o[m][n][2] *= a2; o[m][n][3] *= a3;
        }
      }
      float mm = mj[m];
      float ps = 0.f;
      float p[4][4];
      #pragma unroll
      for (int n = 0; n < 4; n++){
        p[n][0] = __builtin_amdgcn_exp2f(t[n][0] - mm);
        p[n][1] = __builtin_amdgcn_exp2f(t[n][1] - mm);
        p[n][2] = __builtin_amdgcn_exp2f(t[n][2] - mm);
        p[n][3] = __builtin_amdgcn_exp2f(t[n][3] - mm);
        ps += (p[n][0] + p[n][1]) + (p[n][2] + p[n][3]);
      }
      ps += __shfl_xor(ps, 16, 64);
      ps += __shfl_xor(ps, 32, 64);
      lj[m] += ps;
      bf16x8 pa, pb;
      #pragma unroll
      for (int j = 0; j < 4; j++){
        pa[j]   = (bf16_t)p[0][j];
        pa[4+j] = (bf16_t)p[1][j];
        pb[j]   = (bf16_t)p[2][j];
        pb[4+j] = (bf16_t)p[3][j];
      }
      paA[m] = pa; paB[m] = pb;
    }

    // O += P V  (P straight from registers)
    __builtin_amdgcn_s_setprio(1);
    #pragma unroll
    for (int n = 0; n < 4; n++){
      bf16x8 vb0 = *(const bf16x8*)&Vt[(n*16+lr)*72 +      lg*8];
      bf16x8 vb1 = *(const bf16x8*)&Vt[(n*16+lr)*72 + 32 + lg*8];
      if (m0act){
        o[0][n] = mfma16(paA[0], vb0, o[0][n]);
        o[0][n] = mfma16(paB[0], vb1, o[0][n]);
      }
      o[1][n] = mfma16(paA[1], vb0, o[1][n]);
      o[1][n] = mfma16(paB[1], vb1, o[1][n]);
    }
    __builtin_amdgcn_s_setprio(0);
  }

  // normalize + write y (bf16); 1/l transposed to o's row layout via shfl
  #pragma unroll
  for (int m = 0; m < 2; m++){
    float inv = 1.0f / lj[m];
    float i0 = __shfl(inv, lg*4+0, 16);
    float i1 = __shfl(inv, lg*4+1, 16);
    float i2 = __shfl(inv, lg*4+2, 16);
    float i3 = __shfl(inv, lg*4+3, 16);
    const int qb = (m ? qB : qA);
    #pragma unroll
    for (int j = 0; j < 4; j++){
      float ij = (j==0) ? i0 : (j==1) ? i1 : (j==2) ? i2 : i3;
      size_t row = (size_t)b*TT + qb + lg*4 + j;
      #pragma unroll
      for (int n = 0; n < 4; n++)
        y[row*CC + h*HD + n*16 + lr] = f2bf(o[m][n][j] * ij);
    }
  }
}

// ---------------- launch ----------------
extern "C" void kernel_launch(void* const* d_in, const int* in_sizes, int n_in,
                              void* d_out, int out_size, void* d_ws, size_t ws_size,
                              hipStream_t stream){
  const float* x     = (const float*)d_in[0];
  const float* w_in  = (const float*)d_in[1];
  const float* w_out = (const float*)d_in[2];
  float* out = (float*)d_out;

  u16* xb   = (u16*)d_ws;                  // 8192*1024  (reused as y after GEMM1)
  u16* wib  = xb  + (size_t)MM * CC;       // 3072*1024
  u16* wob  = wib + (size_t)C3 * CC;       // 1024*1024
  u16* qkvb = wob + (size_t)CC * CC;       // 8192*3072
  u16* yb   = xb;                          // x is dead after GEMM1

  auto nblk = [](int n8){ int g = (n8 + 255) / 256; return g > 2048 ? 2048 : g; };
  cvt_bf16<<<nblk(MM*CC/8), 256, 0, stream>>>(x,     xb,  MM*CC/8);
  cvt_bf16<<<nblk(C3*CC/8), 256, 0, stream>>>(w_in,  wib, C3*CC/8);
  cvt_bf16<<<nblk(CC*CC/8), 256, 0, stream>>>(w_out, wob, CC*CC/8);

  gemm_bt<1><<<dim3(C3/128, MM/128), 256, 0, stream>>>(xb, wib, (void*)qkvb, MM, C3, CC);
  attn_fwd<<<1024, 256, 0, stream>>>(qkvb, yb);
  gemm_bt<0><<<dim3(CC/128, MM/128), 256, 0, stream>>>(yb, wob, (void*)out, MM, CC, CC);
}

// Round 7
// 172.684 us; speedup vs baseline: 1.7898x; 1.1427x over previous
//
#include <hip/hip_runtime.h>
#include <stdint.h>

#define BB 4
#define TT 2048
#define CC 1024
#define HH 16
#define HD 64
#define C3 3072
#define MM (BB*TT)   // 8192 rows

typedef __bf16 bf16_t;
typedef bf16_t bf16x8 __attribute__((ext_vector_type(8)));
typedef float f32x4 __attribute__((ext_vector_type(4)));
typedef unsigned short u16;
typedef u16 u16x8 __attribute__((ext_vector_type(8)));
typedef uint32_t u32;

// f32 -> bf16 round-to-nearest-even
static __device__ __forceinline__ u16 f2bf(float f){
  u32 u = __builtin_bit_cast(u32, f);
  u32 r = (u + 0x7fffu + ((u >> 16) & 1u)) >> 16;
  return (u16)r;
}

static __device__ __forceinline__ f32x4 mfma16(bf16x8 a, bf16x8 b, f32x4 c){
  return __builtin_amdgcn_mfma_f32_16x16x32_bf16(a, b, c, 0, 0, 0);
}

typedef __attribute__((address_space(1))) void* gas_t;
typedef __attribute__((address_space(3))) void* las_t;
static __device__ __forceinline__ void gload16(const void* g, void* l){
  __builtin_amdgcn_global_load_lds((gas_t)g, (las_t)l, 16, 0, 0);
}

// ---------------- fp32 -> bf16 conversion (vectorized) ----------------
__global__ __launch_bounds__(256) void cvt_bf16(const float* __restrict__ in,
                                                u16* __restrict__ out, int n8){
  int stride = gridDim.x * blockDim.x;
  for (int i = blockIdx.x * blockDim.x + threadIdx.x; i < n8; i += stride){
    const float4* p = (const float4*)in + (size_t)i * 2;
    float4 a = p[0], b = p[1];
    u16x8 o;
    o[0]=f2bf(a.x); o[1]=f2bf(a.y); o[2]=f2bf(a.z); o[3]=f2bf(a.w);
    o[4]=f2bf(b.x); o[5]=f2bf(b.y); o[6]=f2bf(b.z); o[7]=f2bf(b.w);
    *((u16x8*)out + i) = o;
  }
}

// ---------------- bt-GEMM: C[M,N] = A[M,K] * B[N,K]^T ------------------------
// 128x128 tile, BK=64 (half the barriers of BK=32), 256 thr = 4 waves (2x2).
// LDS rows are 128B -> fragment reads XOR-swizzled (slot ^= row&7) to kill the
// 16-way conflict; swizzle applied on the GLOBAL source side (gload_lds writes
// linearly) and on the LDS reads (rule: both-sides-or-neither).
// 1D grid with XCD-chunked swizzle: xcd = bid&7 owns cpx consecutive tiles.
template<int OUTBF>
__global__ __launch_bounds__(256) void gemm_bt(const u16* __restrict__ A,
                                               const u16* __restrict__ Bm,
                                               void* __restrict__ Cp,
                                               int M, int N, int K,
                                               int nbx, int cpx){
  __shared__ u16 As[128*64];
  __shared__ u16 Bs[128*64];
  const int bid = blockIdx.x;
  const int nb = (bid & 7) * cpx + (bid >> 3);
  const int by = nb / nbx, bx = nb - by * nbx;
  const int tid  = threadIdx.x;
  const int lane = tid & 63;
  const int w    = tid >> 6;
  const int m0   = by * 128;
  const int n0   = bx * 128;
  const int wm   = (w >> 1) * 64;
  const int wn   = (w & 1) * 64;
  const int lr   = lane & 15;
  const int lg4  = lane >> 4;        // 0..3

  f32x4 acc[4][4] = {};

  // staging: thread t, chunk q -> LDS byte q*4096 + t*16 (linear);
  // content at (row, slot) = global (row, col-chunk slot ^ (row&7))
  const int rq  = tid >> 3;                          // 0..31
  const int c8s = ((tid & 7) ^ (rq & 7)) * 8;        // pre-swizzled global col
  const u16* gA = A  + (size_t)(m0 + rq) * K + c8s;
  const u16* gB = Bm + (size_t)(n0 + rq) * K + c8s;
  char* lA = (char*)As + tid*16;
  char* lB = (char*)Bs + tid*16;

  for (int k0 = 0; k0 < K; k0 += 64){
    #pragma unroll
    for (int q = 0; q < 4; q++){
      gload16(gA + (size_t)(q*32)*K + k0, lA + q*4096);
      gload16(gB + (size_t)(q*32)*K + k0, lB + q*4096);
    }
    __syncthreads();
    #pragma unroll
    for (int kk = 0; kk < 2; kk++){
      bf16x8 af[4], bfr[4];
      #pragma unroll
      for (int m = 0; m < 4; m++){
        int row = wm + m*16 + lr;
        int slot = ((kk<<2) | lg4) ^ (row & 7);
        af[m] = *(const bf16x8*)((const char*)As + row*128 + slot*16);
      }
      #pragma unroll
      for (int n = 0; n < 4; n++){
        int row = wn + n*16 + lr;
        int slot = ((kk<<2) | lg4) ^ (row & 7);
        bfr[n] = *(const bf16x8*)((const char*)Bs + row*128 + slot*16);
      }
      #pragma unroll
      for (int m = 0; m < 4; m++)
        #pragma unroll
        for (int n = 0; n < 4; n++)
          acc[m][n] = mfma16(af[m], bfr[n], acc[m][n]);
    }
    __syncthreads();
  }

  const int cr = lg4 * 4;
  #pragma unroll
  for (int m = 0; m < 4; m++)
    #pragma unroll
    for (int n = 0; n < 4; n++)
      #pragma unroll
      for (int j = 0; j < 4; j++){
        size_t row = (size_t)(m0 + wm + m*16 + cr + j);
        size_t col = (size_t)(n0 + wn + n*16 + lr);
        if (OUTBF) ((u16*)Cp)[row*(size_t)N + col] = f2bf(acc[m][n][j]);
        else       ((float*)Cp)[row*(size_t)N + col] = acc[m][n][j];
      }
}

// ---------------- flash attention (causal), bf16 in/out ----------------
// Block = q-tile PAIR (tq, 31-tq), constant work. bid = h + 16b + 64tq so
// same-(b,h) blocks are stride-64 (same XCD -> one L2 copy of K/V).
// Swapped QK^T with PERMUTED K-rows; P-quads feed PV natively (no P LDS).
// Q pre-scaled by SC (softmax works on scaled scores directly).
__global__ __launch_bounds__(256, 3) void attn_fwd(const u16* __restrict__ qkv,
                                                   u16* __restrict__ y){
  __shared__ u16 Kl[64*72];      // K tile [k][d], row stride 72, XOR-swizzled
  __shared__ u16 Vt[64*72];      // V^T tile [d][k], row stride 72
  const int bid = blockIdx.x;
  const int tq = bid >> 6;
  const int h = bid & 15, b = (bid >> 4) & 3;
  const int tid = threadIdx.x, lane = tid & 63, w = tid >> 6;
  const int lr = lane & 15, lg = lane >> 4;
  const size_t base = (size_t)b * TT * C3;
  const int qA = tq*64 + w*16;          // m=0 wave q-base
  const int qB = (31-tq)*64 + w*16;     // m=1 wave q-base
  const float SC = 0.18033688011112042f;   // (1/8) * log2(e)

  // Q fragments (B-operand), pre-scaled by SC
  bf16x8 qf[2][2];
  {
    const u16* qp0 = qkv + base + (size_t)(qA + lr) * C3 + h*HD;
    qf[0][0] = *(const bf16x8*)(qp0 + lg*8);
    qf[0][1] = *(const bf16x8*)(qp0 + 32 + lg*8);
    const u16* qp1 = qkv + base + (size_t)(qB + lr) * C3 + h*HD;
    qf[1][0] = *(const bf16x8*)(qp1 + lg*8);
    qf[1][1] = *(const bf16x8*)(qp1 + 32 + lg*8);
    #pragma unroll
    for (int m = 0; m < 2; m++)
      #pragma unroll
      for (int i = 0; i < 2; i++)
        #pragma unroll
        for (int e = 0; e < 8; e++)
          qf[m][i][e] = (bf16_t)((float)qf[m][i][e] * SC);
  }

  // staging maps: K coalesced (row = tid>>3), V k-major lanes (row = tid&31)
  const int rK = tid >> 3, cK = tid & 7;
  const int rV = tid & 31, cV = tid >> 5;
  const u16* gK = qkv + base + (size_t)rK * C3 + CC   + h*HD + cK*8;
  const u16* gV = qkv + base + (size_t)rV * C3 + 2*CC + h*HD + cV*8;

  // swizzled K write indices (key = (row>>3)&1, same for row and row+32)
  const int kkey = ((rK >> 3) & 1) << 5;
  const int kw0 = rK*72 + ((cK*8) ^ kkey);
  const int kw1 = (rK+32)*72 + ((cK*8) ^ kkey);

  // kb read: row rho(n,lr) -> key depends only on (lr>>2)&1
  const int rdx = ((lr >> 2) & 1) << 5;
  const int rbase = 8*(lr >> 2) + (lr & 3);     // row part from lr

  u16x8 kreg[2], vreg[2];
  kreg[0] = *(const u16x8*)(gK);
  kreg[1] = *(const u16x8*)(gK + (size_t)32*C3);
  vreg[0] = *(const u16x8*)(gV);
  vreg[1] = *(const u16x8*)(gV + (size_t)32*C3);

  f32x4 o[2][4] = {};
  float mj[2] = {-1e30f, -1e30f};
  float lj[2] = {0.f, 0.f};

  const int ktmax = 31 - tq;
  for (int kt = 0; kt <= ktmax; kt++){
    __syncthreads();   // previous tile's LDS reads complete
    *(u16x8*)&Kl[kw0] = kreg[0];
    *(u16x8*)&Kl[kw1] = kreg[1];
    #pragma unroll
    for (int i = 0; i < 2; i++)
      #pragma unroll
      for (int e = 0; e < 8; e++)
        Vt[(cV*8+e)*72 + i*32 + rV] = vreg[i][e];
    __syncthreads();

    // prefetch next tile into regs (hides under compute)
    if (kt < ktmax){
      const u16* gk2 = gK + (size_t)(kt+1)*64*C3;
      const u16* gv2 = gV + (size_t)(kt+1)*64*C3;
      kreg[0] = *(const u16x8*)(gk2);
      kreg[1] = *(const u16x8*)(gk2 + (size_t)32*C3);
      vreg[0] = *(const u16x8*)(gv2);
      vreg[1] = *(const u16x8*)(gv2 + (size_t)32*C3);
    }

    const bool m0act = (kt <= tq);

    // S^T via permuted K-rows: lane holds S[q=lr][k=32(n>>1)+8lg+4(n&1)+j]
    f32x4 s[2][4] = {};
    __builtin_amdgcn_s_setprio(1);
    #pragma unroll
    for (int n = 0; n < 4; n++){
      const int rho = 32*(n>>1) + 4*(n&1) + rbase;
      bf16x8 kb0 = *(const bf16x8*)&Kl[rho*72 + ((     lg*8) ^ rdx)];
      bf16x8 kb1 = *(const bf16x8*)&Kl[rho*72 + ((32 + lg*8) ^ rdx)];
      if (m0act){
        s[0][n] = mfma16(kb0, qf[0][0], s[0][n]);
        s[0][n] = mfma16(kb1, qf[0][1], s[0][n]);
      }
      s[1][n] = mfma16(kb0, qf[1][0], s[1][n]);
      s[1][n] = mfma16(kb1, qf[1][1], s[1][n]);
    }
    __builtin_amdgcn_s_setprio(0);

    // online softmax (scores already scaled): mask in place, in-lane reduce
    bf16x8 paA[2], paB[2];
    #pragma unroll
    for (int m = 0; m < 2; m++){
      if (m == 0 && !m0act) continue;
      const int qrow = (m ? qB : qA) + lr;
      const bool dm = (kt == (m ? ktmax : tq));   // diagonal tile for this m
      if (dm){
        #pragma unroll
        for (int n = 0; n < 4; n++)
          #pragma unroll
          for (int j = 0; j < 4; j++)
            if (kt*64 + 32*(n>>1) + 8*lg + 4*(n&1) + j > qrow)
              s[m][n][j] = -1e30f;
      }
      float tm = s[m][0][0];
      #pragma unroll
      for (int n = 0; n < 4; n++)
        #pragma unroll
        for (int j = 0; j < 4; j++) tm = fmaxf(tm, s[m][n][j]);
      tm = fmaxf(tm, __shfl_xor(tm, 16, 64));
      tm = fmaxf(tm, __shfl_xor(tm, 32, 64));
      float mo = mj[m];
      if (!__all(tm <= mo + 4.0f)){   // T13 defer-max, THR=4 (P <= 16)
        float mn = fmaxf(mo, tm);
        float al = __builtin_amdgcn_exp2f(mo - mn);
        mj[m] = mn;
        lj[m] *= al;
        float a0 = __shfl(al, lg*4+0, 16);
        float a1 = __shfl(al, lg*4+1, 16);
        float a2 = __shfl(al, lg*4+2, 16);
        float a3 = __shfl(al, lg*4+3, 16);
        #pragma unroll
        for (int n = 0; n < 4; n++){
          o[m][n][0] *= a0; o[m][n][1] *= a1;
          o[m][n][2] *= a2; o[m][n][3] *= a3;
        }
      }
      float mm = mj[m];
      float ps = 0.f;
      bf16x8 pa, pb;
      #pragma unroll
      for (int n = 0; n < 4; n++){
        float p0 = __builtin_amdgcn_exp2f(s[m][n][0] - mm);
        float p1 = __builtin_amdgcn_exp2f(s[m][n][1] - mm);
        float p2 = __builtin_amdgcn_exp2f(s[m][n][2] - mm);
        float p3 = __builtin_amdgcn_exp2f(s[m][n][3] - mm);
        ps += (p0 + p1) + (p2 + p3);
        if (n == 0){ pa[0]=(bf16_t)p0; pa[1]=(bf16_t)p1; pa[2]=(bf16_t)p2; pa[3]=(bf16_t)p3; }
        if (n == 1){ pa[4]=(bf16_t)p0; pa[5]=(bf16_t)p1; pa[6]=(bf16_t)p2; pa[7]=(bf16_t)p3; }
        if (n == 2){ pb[0]=(bf16_t)p0; pb[1]=(bf16_t)p1; pb[2]=(bf16_t)p2; pb[3]=(bf16_t)p3; }
        if (n == 3){ pb[4]=(bf16_t)p0; pb[5]=(bf16_t)p1; pb[6]=(bf16_t)p2; pb[7]=(bf16_t)p3; }
      }
      ps += __shfl_xor(ps, 16, 64);
      ps += __shfl_xor(ps, 32, 64);
      lj[m] += ps;
      paA[m] = pa; paB[m] = pb;
    }

    // O += P V  (P straight from registers)
    __builtin_amdgcn_s_setprio(1);
    #pragma unroll
    for (int n = 0; n < 4; n++){
      bf16x8 vb0 = *(const bf16x8*)&Vt[(n*16+lr)*72 +      lg*8];
      bf16x8 vb1 = *(const bf16x8*)&Vt[(n*16+lr)*72 + 32 + lg*8];
      if (m0act){
        o[0][n] = mfma16(paA[0], vb0, o[0][n]);
        o[0][n] = mfma16(paB[0], vb1, o[0][n]);
      }
      o[1][n] = mfma16(paA[1], vb0, o[1][n]);
      o[1][n] = mfma16(paB[1], vb1, o[1][n]);
    }
    __builtin_amdgcn_s_setprio(0);
  }

  // normalize + write y (bf16); 1/l transposed to o's row layout via shfl
  #pragma unroll
  for (int m = 0; m < 2; m++){
    float inv = 1.0f / lj[m];
    float i0 = __shfl(inv, lg*4+0, 16);
    float i1 = __shfl(inv, lg*4+1, 16);
    float i2 = __shfl(inv, lg*4+2, 16);
    float i3 = __shfl(inv, lg*4+3, 16);
    const int qb = (m ? qB : qA);
    #pragma unroll
    for (int j = 0; j < 4; j++){
      float ij = (j==0) ? i0 : (j==1) ? i1 : (j==2) ? i2 : i3;
      size_t row = (size_t)b*TT + qb + lg*4 + j;
      #pragma unroll
      for (int n = 0; n < 4; n++)
        y[row*CC + h*HD + n*16 + lr] = f2bf(o[m][n][j] * ij);
    }
  }
}

// ---------------- launch ----------------
extern "C" void kernel_launch(void* const* d_in, const int* in_sizes, int n_in,
                              void* d_out, int out_size, void* d_ws, size_t ws_size,
                              hipStream_t stream){
  const float* x     = (const float*)d_in[0];
  const float* w_in  = (const float*)d_in[1];
  const float* w_out = (const float*)d_in[2];
  float* out = (float*)d_out;

  u16* xb   = (u16*)d_ws;                  // 8192*1024  (reused as y after GEMM1)
  u16* wib  = xb  + (size_t)MM * CC;       // 3072*1024
  u16* wob  = wib + (size_t)C3 * CC;       // 1024*1024
  u16* qkvb = wob + (size_t)CC * CC;       // 8192*3072
  u16* yb   = xb;                          // x is dead after GEMM1

  auto nblk = [](int n8){ int g = (n8 + 255) / 256; return g > 2048 ? 2048 : g; };
  cvt_bf16<<<nblk(MM*CC/8), 256, 0, stream>>>(x,     xb,  MM*CC/8);
  cvt_bf16<<<nblk(C3*CC/8), 256, 0, stream>>>(w_in,  wib, C3*CC/8);
  cvt_bf16<<<nblk(CC*CC/8), 256, 0, stream>>>(w_out, wob, CC*CC/8);

  // GEMM1: 8192x3072x1024 -> grid 64x24 = 1536 blocks, 192/XCD
  gemm_bt<1><<<1536, 256, 0, stream>>>(xb, wib, (void*)qkvb, MM, C3, CC, 24, 192);
  attn_fwd<<<1024, 256, 0, stream>>>(qkvb, yb);
  // GEMM2: 8192x1024x1024 -> grid 64x8 = 512 blocks, 64/XCD
  gemm_bt<0><<<512, 256, 0, stream>>>(yb, wob, (void*)out, MM, CC, CC, 8, 64);
}

// Round 8
// 172.404 us; speedup vs baseline: 1.7927x; 1.0016x over previous
//
#include <hip/hip_runtime.h>
#include <stdint.h>

#define BB 4
#define TT 2048
#define CC 1024
#define HH 16
#define HD 64
#define C3 3072
#define MM (BB*TT)   // 8192 rows

typedef __bf16 bf16_t;
typedef bf16_t bf16x8 __attribute__((ext_vector_type(8)));
typedef float f32x4 __attribute__((ext_vector_type(4)));
typedef unsigned short u16;
typedef u16 u16x8 __attribute__((ext_vector_type(8)));
typedef uint32_t u32;

// f32 -> bf16 round-to-nearest-even
static __device__ __forceinline__ u16 f2bf(float f){
  u32 u = __builtin_bit_cast(u32, f);
  u32 r = (u + 0x7fffu + ((u >> 16) & 1u)) >> 16;
  return (u16)r;
}

static __device__ __forceinline__ f32x4 mfma16(bf16x8 a, bf16x8 b, f32x4 c){
  return __builtin_amdgcn_mfma_f32_16x16x32_bf16(a, b, c, 0, 0, 0);
}

typedef __attribute__((address_space(1))) void* gas_t;
typedef __attribute__((address_space(3))) void* las_t;
static __device__ __forceinline__ void gload16(const void* g, void* l){
  __builtin_amdgcn_global_load_lds((gas_t)g, (las_t)l, 16, 0, 0);
}

// ---------------- fp32 -> bf16 conversion (vectorized) ----------------
__global__ __launch_bounds__(256) void cvt_bf16(const float* __restrict__ in,
                                                u16* __restrict__ out, int n8){
  int stride = gridDim.x * blockDim.x;
  for (int i = blockIdx.x * blockDim.x + threadIdx.x; i < n8; i += stride){
    const float4* p = (const float4*)in + (size_t)i * 2;
    float4 a = p[0], b = p[1];
    u16x8 o;
    o[0]=f2bf(a.x); o[1]=f2bf(a.y); o[2]=f2bf(a.z); o[3]=f2bf(a.w);
    o[4]=f2bf(b.x); o[5]=f2bf(b.y); o[6]=f2bf(b.z); o[7]=f2bf(b.w);
    *((u16x8*)out + i) = o;
  }
}

// ---------------- bt-GEMM: C[M,N] = A[M,K] * B[N,K]^T ------------------------
// 128x128 tile, BK=64, 256 thr = 4 waves (2x2). LDS reads XOR-swizzled
// (slot ^= row&7) via pre-swizzled global source (gload_lds writes linearly).
// 1D grid with XCD-chunked swizzle: xcd = bid&7 owns cpx consecutive tiles.
template<int OUTBF>
__global__ __launch_bounds__(256) void gemm_bt(const u16* __restrict__ A,
                                               const u16* __restrict__ Bm,
                                               void* __restrict__ Cp,
                                               int M, int N, int K,
                                               int nbx, int cpx){
  __shared__ u16 As[128*64];
  __shared__ u16 Bs[128*64];
  const int bid = blockIdx.x;
  const int nb = (bid & 7) * cpx + (bid >> 3);
  const int by = nb / nbx, bx = nb - by * nbx;
  const int tid  = threadIdx.x;
  const int lane = tid & 63;
  const int w    = tid >> 6;
  const int m0   = by * 128;
  const int n0   = bx * 128;
  const int wm   = (w >> 1) * 64;
  const int wn   = (w & 1) * 64;
  const int lr   = lane & 15;
  const int lg4  = lane >> 4;        // 0..3

  f32x4 acc[4][4] = {};

  const int rq  = tid >> 3;                          // 0..31
  const int c8s = ((tid & 7) ^ (rq & 7)) * 8;        // pre-swizzled global col
  const u16* gA = A  + (size_t)(m0 + rq) * K + c8s;
  const u16* gB = Bm + (size_t)(n0 + rq) * K + c8s;
  char* lA = (char*)As + tid*16;
  char* lB = (char*)Bs + tid*16;

  for (int k0 = 0; k0 < K; k0 += 64){
    #pragma unroll
    for (int q = 0; q < 4; q++){
      gload16(gA + (size_t)(q*32)*K + k0, lA + q*4096);
      gload16(gB + (size_t)(q*32)*K + k0, lB + q*4096);
    }
    __syncthreads();
    #pragma unroll
    for (int kk = 0; kk < 2; kk++){
      bf16x8 af[4], bfr[4];
      #pragma unroll
      for (int m = 0; m < 4; m++){
        int row = wm + m*16 + lr;
        int slot = ((kk<<2) | lg4) ^ (row & 7);
        af[m] = *(const bf16x8*)((const char*)As + row*128 + slot*16);
      }
      #pragma unroll
      for (int n = 0; n < 4; n++){
        int row = wn + n*16 + lr;
        int slot = ((kk<<2) | lg4) ^ (row & 7);
        bfr[n] = *(const bf16x8*)((const char*)Bs + row*128 + slot*16);
      }
      #pragma unroll
      for (int m = 0; m < 4; m++)
        #pragma unroll
        for (int n = 0; n < 4; n++)
          acc[m][n] = mfma16(af[m], bfr[n], acc[m][n]);
    }
    __syncthreads();
  }

  const int cr = lg4 * 4;
  #pragma unroll
  for (int m = 0; m < 4; m++)
    #pragma unroll
    for (int n = 0; n < 4; n++)
      #pragma unroll
      for (int j = 0; j < 4; j++){
        size_t row = (size_t)(m0 + wm + m*16 + cr + j);
        size_t col = (size_t)(n0 + wn + n*16 + lr);
        if (OUTBF) ((u16*)Cp)[row*(size_t)N + col] = f2bf(acc[m][n][j]);
        else       ((float*)Cp)[row*(size_t)N + col] = acc[m][n][j];
      }
}

// ---------------- flash attention (causal), bf16 in/out ----------------
// Block = q-tile PAIR (tq, 31-tq), constant work. bid = h + 16b + 64tq so
// same-(b,h) blocks are stride-64 (same XCD -> one L2 copy of K/V).
// Swapped QK^T with PERMUTED K-rows; P-quads feed PV natively (no P LDS).
// Q pre-scaled by SC. DOUBLE-BUFFERED K/V LDS: one barrier per k-tile;
// paired V staging (adjacent k-rows) -> 8 x b32 transpose writes.
__global__ __launch_bounds__(256, 3) void attn_fwd(const u16* __restrict__ qkv,
                                                   u16* __restrict__ y){
  __shared__ u16 Kl[2][64*72];   // K tile [k][d], row stride 72, XOR-swizzled
  __shared__ u16 Vt[2][64*72];   // V^T tile [d][k], row stride 72
  const int bid = blockIdx.x;
  const int tq = bid >> 6;
  const int h = bid & 15, b = (bid >> 4) & 3;
  const int tid = threadIdx.x, lane = tid & 63, w = tid >> 6;
  const int lr = lane & 15, lg = lane >> 4;
  const size_t base = (size_t)b * TT * C3;
  const int qA = tq*64 + w*16;          // m=0 wave q-base
  const int qB = (31-tq)*64 + w*16;     // m=1 wave q-base
  const float SC = 0.18033688011112042f;   // (1/8) * log2(e)

  // Q fragments (B-operand), pre-scaled by SC
  bf16x8 qf[2][2];
  {
    const u16* qp0 = qkv + base + (size_t)(qA + lr) * C3 + h*HD;
    qf[0][0] = *(const bf16x8*)(qp0 + lg*8);
    qf[0][1] = *(const bf16x8*)(qp0 + 32 + lg*8);
    const u16* qp1 = qkv + base + (size_t)(qB + lr) * C3 + h*HD;
    qf[1][0] = *(const bf16x8*)(qp1 + lg*8);
    qf[1][1] = *(const bf16x8*)(qp1 + 32 + lg*8);
    #pragma unroll
    for (int m = 0; m < 2; m++)
      #pragma unroll
      for (int i = 0; i < 2; i++)
        #pragma unroll
        for (int e = 0; e < 8; e++)
          qf[m][i][e] = (bf16_t)((float)qf[m][i][e] * SC);
  }

  // K staging: row = tid>>3 (coalesced);  V staging: adjacent k-row pair
  const int rK = tid >> 3, cK = tid & 7;
  const int rp = tid & 15;            // k-pair: rows 2rp, 2rp+1
  const int dc = (tid >> 4) & 7;      // d-chunk
  const int hf = tid >> 7;            // +32 k half
  const u16* gK = qkv + base + (size_t)rK * C3 + CC + h*HD + cK*8;
  const u16* gV = qkv + base + (size_t)(2*rp + 32*hf) * C3 + 2*CC + h*HD + dc*8;

  // swizzled K write indices (key = (row>>3)&1, same for row and row+32)
  const int kkey = ((rK >> 3) & 1) << 5;
  const int kw0 = rK*72 + ((cK*8) ^ kkey);
  const int kw1 = (rK+32)*72 + ((cK*8) ^ kkey);
  const int vw  = 2*rp + 32*hf;       // V^T col base for this thread

  // kb read: row rho(n,lr) -> key depends only on (lr>>2)&1
  const int rdx = ((lr >> 2) & 1) << 5;
  const int rbase = 8*(lr >> 2) + (lr & 3);     // row part from lr

  u16x8 kreg[2], vreg[2];
  kreg[0] = *(const u16x8*)(gK);
  kreg[1] = *(const u16x8*)(gK + (size_t)32*C3);
  vreg[0] = *(const u16x8*)(gV);
  vreg[1] = *(const u16x8*)(gV + C3);

  f32x4 o[2][4] = {};
  float mj[2] = {-1e30f, -1e30f};
  float lj[2] = {0.f, 0.f};

  const int ktmax = 31 - tq;
  for (int kt = 0; kt <= ktmax; kt++){
    const int cb = kt & 1;
    u16* KL = Kl[cb];
    u16* VT = Vt[cb];
    // stage current tile (regs -> LDS); overlaps other waves' prev compute
    *(u16x8*)&KL[kw0] = kreg[0];
    *(u16x8*)&KL[kw1] = kreg[1];
    #pragma unroll
    for (int e = 0; e < 8; e++){
      u32 pk = (u32)vreg[0][e] | ((u32)vreg[1][e] << 16);
      *(u32*)&VT[(dc*8+e)*72 + vw] = pk;
    }
    __syncthreads();

    // prefetch next tile into regs (hides under compute)
    if (kt < ktmax){
      const u16* gk2 = gK + (size_t)(kt+1)*64*C3;
      const u16* gv2 = gV + (size_t)(kt+1)*64*C3;
      kreg[0] = *(const u16x8*)(gk2);
      kreg[1] = *(const u16x8*)(gk2 + (size_t)32*C3);
      vreg[0] = *(const u16x8*)(gv2);
      vreg[1] = *(const u16x8*)(gv2 + C3);
    }

    const bool m0act = (kt <= tq);

    // S^T via permuted K-rows: lane holds S[q=lr][k=32(n>>1)+8lg+4(n&1)+j]
    f32x4 s[2][4] = {};
    __builtin_amdgcn_s_setprio(1);
    #pragma unroll
    for (int n = 0; n < 4; n++){
      const int rho = 32*(n>>1) + 4*(n&1) + rbase;
      bf16x8 kb0 = *(const bf16x8*)&KL[rho*72 + ((     lg*8) ^ rdx)];
      bf16x8 kb1 = *(const bf16x8*)&KL[rho*72 + ((32 + lg*8) ^ rdx)];
      if (m0act){
        s[0][n] = mfma16(kb0, qf[0][0], s[0][n]);
        s[0][n] = mfma16(kb1, qf[0][1], s[0][n]);
      }
      s[1][n] = mfma16(kb0, qf[1][0], s[1][n]);
      s[1][n] = mfma16(kb1, qf[1][1], s[1][n]);
    }
    __builtin_amdgcn_s_setprio(0);

    // online softmax (scores already scaled): mask in place, in-lane reduce
    bf16x8 paA[2], paB[2];
    #pragma unroll
    for (int m = 0; m < 2; m++){
      if (m == 0 && !m0act) continue;
      const int qrow = (m ? qB : qA) + lr;
      const bool dm = (kt == (m ? ktmax : tq));   // diagonal tile for this m
      if (dm){
        #pragma unroll
        for (int n = 0; n < 4; n++)
          #pragma unroll
          for (int j = 0; j < 4; j++)
            if (kt*64 + 32*(n>>1) + 8*lg + 4*(n&1) + j > qrow)
              s[m][n][j] = -1e30f;
      }
      float tm = s[m][0][0];
      #pragma unroll
      for (int n = 0; n < 4; n++)
        #pragma unroll
        for (int j = 0; j < 4; j++) tm = fmaxf(tm, s[m][n][j]);
      tm = fmaxf(tm, __shfl_xor(tm, 16, 64));
      tm = fmaxf(tm, __shfl_xor(tm, 32, 64));
      float mo = mj[m];
      if (!__all(tm <= mo + 4.0f)){   // T13 defer-max, THR=4 (P <= 16)
        float mn = fmaxf(mo, tm);
        float al = __builtin_amdgcn_exp2f(mo - mn);
        mj[m] = mn;
        lj[m] *= al;
        float a0 = __shfl(al, lg*4+0, 16);
        float a1 = __shfl(al, lg*4+1, 16);
        float a2 = __shfl(al, lg*4+2, 16);
        float a3 = __shfl(al, lg*4+3, 16);
        #pragma unroll
        for (int n = 0; n < 4; n++){
          o[m][n][0] *= a0; o[m][n][1] *= a1;
          o[m][n][2] *= a2; o[m][n][3] *= a3;
        }
      }
      float mm = mj[m];
      float ps = 0.f;
      bf16x8 pa, pb;
      #pragma unroll
      for (int n = 0; n < 4; n++){
        float p0 = __builtin_amdgcn_exp2f(s[m][n][0] - mm);
        float p1 = __builtin_amdgcn_exp2f(s[m][n][1] - mm);
        float p2 = __builtin_amdgcn_exp2f(s[m][n][2] - mm);
        float p3 = __builtin_amdgcn_exp2f(s[m][n][3] - mm);
        ps += (p0 + p1) + (p2 + p3);
        if (n == 0){ pa[0]=(bf16_t)p0; pa[1]=(bf16_t)p1; pa[2]=(bf16_t)p2; pa[3]=(bf16_t)p3; }
        if (n == 1){ pa[4]=(bf16_t)p0; pa[5]=(bf16_t)p1; pa[6]=(bf16_t)p2; pa[7]=(bf16_t)p3; }
        if (n == 2){ pb[0]=(bf16_t)p0; pb[1]=(bf16_t)p1; pb[2]=(bf16_t)p2; pb[3]=(bf16_t)p3; }
        if (n == 3){ pb[4]=(bf16_t)p0; pb[5]=(bf16_t)p1; pb[6]=(bf16_t)p2; pb[7]=(bf16_t)p3; }
      }
      ps += __shfl_xor(ps, 16, 64);
      ps += __shfl_xor(ps, 32, 64);
      lj[m] += ps;
      paA[m] = pa; paB[m] = pb;
    }

    // O += P V  (P straight from registers)
    __builtin_amdgcn_s_setprio(1);
    #pragma unroll
    for (int n = 0; n < 4; n++){
      bf16x8 vb0 = *(const bf16x8*)&VT[(n*16+lr)*72 +      lg*8];
      bf16x8 vb1 = *(const bf16x8*)&VT[(n*16+lr)*72 + 32 + lg*8];
      if (m0act){
        o[0][n] = mfma16(paA[0], vb0, o[0][n]);
        o[0][n] = mfma16(paB[0], vb1, o[0][n]);
      }
      o[1][n] = mfma16(paA[1], vb0, o[1][n]);
      o[1][n] = mfma16(paB[1], vb1, o[1][n]);
    }
    __builtin_amdgcn_s_setprio(0);
  }

  // normalize + write y (bf16); 1/l transposed to o's row layout via shfl
  #pragma unroll
  for (int m = 0; m < 2; m++){
    float inv = 1.0f / lj[m];
    float i0 = __shfl(inv, lg*4+0, 16);
    float i1 = __shfl(inv, lg*4+1, 16);
    float i2 = __shfl(inv, lg*4+2, 16);
    float i3 = __shfl(inv, lg*4+3, 16);
    const int qb = (m ? qB : qA);
    #pragma unroll
    for (int j = 0; j < 4; j++){
      float ij = (j==0) ? i0 : (j==1) ? i1 : (j==2) ? i2 : i3;
      size_t row = (size_t)b*TT + qb + lg*4 + j;
      #pragma unroll
      for (int n = 0; n < 4; n++)
        y[row*CC + h*HD + n*16 + lr] = f2bf(o[m][n][j] * ij);
    }
  }
}

// ---------------- launch ----------------
extern "C" void kernel_launch(void* const* d_in, const int* in_sizes, int n_in,
                              void* d_out, int out_size, void* d_ws, size_t ws_size,
                              hipStream_t stream){
  const float* x     = (const float*)d_in[0];
  const float* w_in  = (const float*)d_in[1];
  const float* w_out = (const float*)d_in[2];
  float* out = (float*)d_out;

  u16* xb   = (u16*)d_ws;                  // 8192*1024  (reused as y after GEMM1)
  u16* wib  = xb  + (size_t)MM * CC;       // 3072*1024
  u16* wob  = wib + (size_t)C3 * CC;       // 1024*1024
  u16* qkvb = wob + (size_t)CC * CC;       // 8192*3072
  u16* yb   = xb;                          // x is dead after GEMM1

  auto nblk = [](int n8){ int g = (n8 + 255) / 256; return g > 2048 ? 2048 : g; };
  cvt_bf16<<<nblk(MM*CC/8), 256, 0, stream>>>(x,     xb,  MM*CC/8);
  cvt_bf16<<<nblk(C3*CC/8), 256, 0, stream>>>(w_in,  wib, C3*CC/8);
  cvt_bf16<<<nblk(CC*CC/8), 256, 0, stream>>>(w_out, wob, CC*CC/8);

  // GEMM1: 8192x3072x1024 -> grid 64x24 = 1536 blocks, 192/XCD
  gemm_bt<1><<<1536, 256, 0, stream>>>(xb, wib, (void*)qkvb, MM, C3, CC, 24, 192);
  attn_fwd<<<1024, 256, 0, stream>>>(qkvb, yb);
  // GEMM2: 8192x1024x1024 -> grid 64x8 = 512 blocks, 64/XCD
  gemm_bt<0><<<512, 256, 0, stream>>>(yb, wob, (void*)out, MM, CC, CC, 8, 64);
}

// Round 9
// 166.916 us; speedup vs baseline: 1.8516x; 1.0329x over previous
//
#include <hip/hip_runtime.h>
#include <stdint.h>

#define BB 4
#define TT 2048
#define CC 1024
#define HH 16
#define HD 64
#define C3 3072
#define MM (BB*TT)   // 8192 rows

typedef __bf16 bf16_t;
typedef bf16_t bf16x8 __attribute__((ext_vector_type(8)));
typedef float f32x4 __attribute__((ext_vector_type(4)));
typedef unsigned short u16;
typedef u16 u16x8 __attribute__((ext_vector_type(8)));
typedef uint32_t u32;

// f32 -> bf16 round-to-nearest-even
static __device__ __forceinline__ u16 f2bf(float f){
  u32 u = __builtin_bit_cast(u32, f);
  u32 r = (u + 0x7fffu + ((u >> 16) & 1u)) >> 16;
  return (u16)r;
}

static __device__ __forceinline__ f32x4 mfma16(bf16x8 a, bf16x8 b, f32x4 c){
  return __builtin_amdgcn_mfma_f32_16x16x32_bf16(a, b, c, 0, 0, 0);
}

typedef __attribute__((address_space(1))) void* gas_t;
typedef __attribute__((address_space(3))) void* las_t;
static __device__ __forceinline__ void gload16(const void* g, void* l){
  __builtin_amdgcn_global_load_lds((gas_t)g, (las_t)l, 16, 0, 0);
}

// ---------------- fp32 -> bf16 conversion (all three inputs, one kernel) -----
// ws layout [xb | wib | wob] is contiguous -> single output pointer.
__global__ __launch_bounds__(256) void cvt_all(const float* __restrict__ x,
                                               const float* __restrict__ wi,
                                               const float* __restrict__ wo,
                                               u16* __restrict__ out){
  const int n1 = MM*CC/8, n2 = C3*CC/8, n3 = CC*CC/8;
  const int total = n1 + n2 + n3;
  int stride = gridDim.x * blockDim.x;
  for (int i = blockIdx.x * blockDim.x + threadIdx.x; i < total; i += stride){
    const float* src; int k;
    if (i < n1){ src = x; k = i; }
    else if (i < n1 + n2){ src = wi; k = i - n1; }
    else { src = wo; k = i - n1 - n2; }
    const float4* p = (const float4*)src + (size_t)k * 2;
    float4 a = p[0], b = p[1];
    u16x8 o;
    o[0]=f2bf(a.x); o[1]=f2bf(a.y); o[2]=f2bf(a.z); o[3]=f2bf(a.w);
    o[4]=f2bf(b.x); o[5]=f2bf(b.y); o[6]=f2bf(b.z); o[7]=f2bf(b.w);
    *((u16x8*)out + i) = o;
  }
}

// ---------------- bt-GEMM: C[M,N] = A[M,K] * B[N,K]^T ------------------------
// 128x128 tile, BK=64, 256 thr = 4 waves (2x2). LDS reads XOR-swizzled
// (slot ^= row&7) via pre-swizzled global source (gload_lds writes linearly).
// 1D grid with XCD-chunked swizzle: xcd = bid&7 owns cpx consecutive tiles.
template<int OUTBF>
__global__ __launch_bounds__(256) void gemm_bt(const u16* __restrict__ A,
                                               const u16* __restrict__ Bm,
                                               void* __restrict__ Cp,
                                               int M, int N, int K,
                                               int nbx, int cpx){
  __shared__ u16 As[128*64];
  __shared__ u16 Bs[128*64];
  const int bid = blockIdx.x;
  const int nb = (bid & 7) * cpx + (bid >> 3);
  const int by = nb / nbx, bx = nb - by * nbx;
  const int tid  = threadIdx.x;
  const int lane = tid & 63;
  const int w    = tid >> 6;
  const int m0   = by * 128;
  const int n0   = bx * 128;
  const int wm   = (w >> 1) * 64;
  const int wn   = (w & 1) * 64;
  const int lr   = lane & 15;
  const int lg4  = lane >> 4;        // 0..3

  f32x4 acc[4][4] = {};

  const int rq  = tid >> 3;                          // 0..31
  const int c8s = ((tid & 7) ^ (rq & 7)) * 8;        // pre-swizzled global col
  const u16* gA = A  + (size_t)(m0 + rq) * K + c8s;
  const u16* gB = Bm + (size_t)(n0 + rq) * K + c8s;
  char* lA = (char*)As + tid*16;
  char* lB = (char*)Bs + tid*16;

  for (int k0 = 0; k0 < K; k0 += 64){
    #pragma unroll
    for (int q = 0; q < 4; q++){
      gload16(gA + (size_t)(q*32)*K + k0, lA + q*4096);
      gload16(gB + (size_t)(q*32)*K + k0, lB + q*4096);
    }
    __syncthreads();
    #pragma unroll
    for (int kk = 0; kk < 2; kk++){
      bf16x8 af[4], bfr[4];
      #pragma unroll
      for (int m = 0; m < 4; m++){
        int row = wm + m*16 + lr;
        int slot = ((kk<<2) | lg4) ^ (row & 7);
        af[m] = *(const bf16x8*)((const char*)As + row*128 + slot*16);
      }
      #pragma unroll
      for (int n = 0; n < 4; n++){
        int row = wn + n*16 + lr;
        int slot = ((kk<<2) | lg4) ^ (row & 7);
        bfr[n] = *(const bf16x8*)((const char*)Bs + row*128 + slot*16);
      }
      #pragma unroll
      for (int m = 0; m < 4; m++)
        #pragma unroll
        for (int n = 0; n < 4; n++)
          acc[m][n] = mfma16(af[m], bfr[n], acc[m][n]);
    }
    __syncthreads();
  }

  const int cr = lg4 * 4;
  #pragma unroll
  for (int m = 0; m < 4; m++)
    #pragma unroll
    for (int n = 0; n < 4; n++)
      #pragma unroll
      for (int j = 0; j < 4; j++){
        size_t row = (size_t)(m0 + wm + m*16 + cr + j);
        size_t col = (size_t)(n0 + wn + n*16 + lr);
        if (OUTBF) ((u16*)Cp)[row*(size_t)N + col] = f2bf(acc[m][n][j]);
        else       ((float*)Cp)[row*(size_t)N + col] = acc[m][n][j];
      }
}

// ---------------- flash attention (causal), bf16 in/out ----------------
// Block = q-tile PAIR (tq, 31-tq), constant work. bid = h + 16b + 64tq so
// same-(b,h) blocks are stride-64 (same XCD -> one L2 copy of K/V).
// Swapped QK^T with PERMUTED K-rows; P-quads feed PV natively (no P LDS).
// SEQUENTIAL per-m {QK, softmax, PV}: only one S tile (16 regs) and one
// P pack (8 regs) live at a time -> register diet for 3 blocks/CU.
__global__ __launch_bounds__(256, 3) void attn_fwd(const u16* __restrict__ qkv,
                                                   u16* __restrict__ y){
  __shared__ u16 Kl[2][64*72];   // K tile [k][d], row stride 72, XOR-swizzled
  __shared__ u16 Vt[2][64*72];   // V^T tile [d][k], row stride 72
  const int bid = blockIdx.x;
  const int tq = bid >> 6;
  const int h = bid & 15, b = (bid >> 4) & 3;
  const int tid = threadIdx.x, lane = tid & 63, w = tid >> 6;
  const int lr = lane & 15, lg = lane >> 4;
  const size_t base = (size_t)b * TT * C3;
  const int qA = tq*64 + w*16;          // m=0 wave q-base
  const int qB = (31-tq)*64 + w*16;     // m=1 wave q-base
  const float SC = 0.18033688011112042f;   // (1/8) * log2(e)

  // Q fragments (B-operand), pre-scaled by SC
  bf16x8 qf[2][2];
  {
    const u16* qp0 = qkv + base + (size_t)(qA + lr) * C3 + h*HD;
    qf[0][0] = *(const bf16x8*)(qp0 + lg*8);
    qf[0][1] = *(const bf16x8*)(qp0 + 32 + lg*8);
    const u16* qp1 = qkv + base + (size_t)(qB + lr) * C3 + h*HD;
    qf[1][0] = *(const bf16x8*)(qp1 + lg*8);
    qf[1][1] = *(const bf16x8*)(qp1 + 32 + lg*8);
    #pragma unroll
    for (int m = 0; m < 2; m++)
      #pragma unroll
      for (int i = 0; i < 2; i++)
        #pragma unroll
        for (int e = 0; e < 8; e++)
          qf[m][i][e] = (bf16_t)((float)qf[m][i][e] * SC);
  }

  // K staging: row = tid>>3 (coalesced);  V staging: adjacent k-row pair
  const int rK = tid >> 3, cK = tid & 7;
  const int rp = tid & 15;            // k-pair: rows 2rp, 2rp+1
  const int dc = (tid >> 4) & 7;      // d-chunk
  const int hf = tid >> 7;            // +32 k half
  const u16* gK = qkv + base + (size_t)rK * C3 + CC + h*HD + cK*8;
  const u16* gV = qkv + base + (size_t)(2*rp + 32*hf) * C3 + 2*CC + h*HD + dc*8;

  // swizzled K write indices (key = (row>>3)&1, same for row and row+32)
  const int kkey = ((rK >> 3) & 1) << 5;
  const int kw0 = rK*72 + ((cK*8) ^ kkey);
  const int kw1 = (rK+32)*72 + ((cK*8) ^ kkey);
  const int vw  = 2*rp + 32*hf;       // V^T col base for this thread

  // kb read: row rho(n,lr) -> key depends only on (lr>>2)&1
  const int rdx = ((lr >> 2) & 1) << 5;
  const int rbase = 8*(lr >> 2) + (lr & 3);     // row part from lr

  u16x8 kreg[2], vreg[2];
  kreg[0] = *(const u16x8*)(gK);
  kreg[1] = *(const u16x8*)(gK + (size_t)32*C3);
  vreg[0] = *(const u16x8*)(gV);
  vreg[1] = *(const u16x8*)(gV + C3);

  f32x4 o[2][4] = {};
  float mj[2] = {-1e30f, -1e30f};
  float lj[2] = {0.f, 0.f};

  const int ktmax = 31 - tq;
  for (int kt = 0; kt <= ktmax; kt++){
    const int cb = kt & 1;
    u16* KL = Kl[cb];
    u16* VT = Vt[cb];
    // stage current tile (regs -> LDS); overlaps other waves' prev compute
    *(u16x8*)&KL[kw0] = kreg[0];
    *(u16x8*)&KL[kw1] = kreg[1];
    #pragma unroll
    for (int e = 0; e < 8; e++){
      u32 pk = (u32)vreg[0][e] | ((u32)vreg[1][e] << 16);
      *(u32*)&VT[(dc*8+e)*72 + vw] = pk;
    }
    __syncthreads();

    // prefetch next tile into regs (hides under compute)
    if (kt < ktmax){
      const u16* gk2 = gK + (size_t)(kt+1)*64*C3;
      const u16* gv2 = gV + (size_t)(kt+1)*64*C3;
      kreg[0] = *(const u16x8*)(gk2);
      kreg[1] = *(const u16x8*)(gk2 + (size_t)32*C3);
      vreg[0] = *(const u16x8*)(gv2);
      vreg[1] = *(const u16x8*)(gv2 + C3);
    }

    const bool m0act = (kt <= tq);

    // sequential per-m: {QK, softmax, PV} with only one S/P set live
    #pragma unroll
    for (int m = 1; m >= 0; m--){
      if (m == 0 && !m0act) continue;

      // S^T via permuted K-rows: lane holds S[q=lr][k=32(n>>1)+8lg+4(n&1)+j]
      f32x4 s[4] = {};
      __builtin_amdgcn_s_setprio(1);
      #pragma unroll
      for (int n = 0; n < 4; n++){
        const int rho = 32*(n>>1) + 4*(n&1) + rbase;
        bf16x8 kb0 = *(const bf16x8*)&KL[rho*72 + ((     lg*8) ^ rdx)];
        bf16x8 kb1 = *(const bf16x8*)&KL[rho*72 + ((32 + lg*8) ^ rdx)];
        s[n] = mfma16(kb0, qf[m][0], s[n]);
        s[n] = mfma16(kb1, qf[m][1], s[n]);
      }
      __builtin_amdgcn_s_setprio(0);

      // online softmax (scores pre-scaled): mask in place, in-lane reduce
      const int qrow = (m ? qB : qA) + lr;
      const bool dm = (kt == (m ? ktmax : tq));   // diagonal tile for this m
      if (dm){
        #pragma unroll
        for (int n = 0; n < 4; n++)
          #pragma unroll
          for (int j = 0; j < 4; j++)
            if (kt*64 + 32*(n>>1) + 8*lg + 4*(n&1) + j > qrow)
              s[n][j] = -1e30f;
      }
      float tm = s[0][0];
      #pragma unroll
      for (int n = 0; n < 4; n++)
        #pragma unroll
        for (int j = 0; j < 4; j++) tm = fmaxf(tm, s[n][j]);
      tm = fmaxf(tm, __shfl_xor(tm, 16, 64));
      tm = fmaxf(tm, __shfl_xor(tm, 32, 64));
      float mo = mj[m];
      if (!__all(tm <= mo + 4.0f)){   // T13 defer-max, THR=4 (P <= 16)
        float mn = fmaxf(mo, tm);
        float al = __builtin_amdgcn_exp2f(mo - mn);
        mj[m] = mn;
        lj[m] *= al;
        float a0 = __shfl(al, lg*4+0, 16);
        float a1 = __shfl(al, lg*4+1, 16);
        float a2 = __shfl(al, lg*4+2, 16);
        float a3 = __shfl(al, lg*4+3, 16);
        #pragma unroll
        for (int n = 0; n < 4; n++){
          o[m][n][0] *= a0; o[m][n][1] *= a1;
          o[m][n][2] *= a2; o[m][n][3] *= a3;
        }
      }
      float mm = mj[m];
      float ps = 0.f;
      bf16x8 pa, pb;
      #pragma unroll
      for (int n = 0; n < 4; n++){
        float p0 = __builtin_amdgcn_exp2f(s[n][0] - mm);
        float p1 = __builtin_amdgcn_exp2f(s[n][1] - mm);
        float p2 = __builtin_amdgcn_exp2f(s[n][2] - mm);
        float p3 = __builtin_amdgcn_exp2f(s[n][3] - mm);
        ps += (p0 + p1) + (p2 + p3);
        if (n == 0){ pa[0]=(bf16_t)p0; pa[1]=(bf16_t)p1; pa[2]=(bf16_t)p2; pa[3]=(bf16_t)p3; }
        if (n == 1){ pa[4]=(bf16_t)p0; pa[5]=(bf16_t)p1; pa[6]=(bf16_t)p2; pa[7]=(bf16_t)p3; }
        if (n == 2){ pb[0]=(bf16_t)p0; pb[1]=(bf16_t)p1; pb[2]=(bf16_t)p2; pb[3]=(bf16_t)p3; }
        if (n == 3){ pb[4]=(bf16_t)p0; pb[5]=(bf16_t)p1; pb[6]=(bf16_t)p2; pb[7]=(bf16_t)p3; }
      }
      ps += __shfl_xor(ps, 16, 64);
      ps += __shfl_xor(ps, 32, 64);
      lj[m] += ps;

      // O[m] += P V  (P straight from registers)
      __builtin_amdgcn_s_setprio(1);
      #pragma unroll
      for (int n = 0; n < 4; n++){
        bf16x8 vb0 = *(const bf16x8*)&VT[(n*16+lr)*72 +      lg*8];
        bf16x8 vb1 = *(const bf16x8*)&VT[(n*16+lr)*72 + 32 + lg*8];
        o[m][n] = mfma16(pa, vb0, o[m][n]);
        o[m][n] = mfma16(pb, vb1, o[m][n]);
      }
      __builtin_amdgcn_s_setprio(0);
      __builtin_amdgcn_sched_barrier(0);   // keep the two m-bodies separate
    }
  }

  // normalize + write y (bf16); 1/l transposed to o's row layout via shfl
  #pragma unroll
  for (int m = 0; m < 2; m++){
    float inv = 1.0f / lj[m];
    float i0 = __shfl(inv, lg*4+0, 16);
    float i1 = __shfl(inv, lg*4+1, 16);
    float i2 = __shfl(inv, lg*4+2, 16);
    float i3 = __shfl(inv, lg*4+3, 16);
    const int qb = (m ? qB : qA);
    #pragma unroll
    for (int j = 0; j < 4; j++){
      float ij = (j==0) ? i0 : (j==1) ? i1 : (j==2) ? i2 : i3;
      size_t row = (size_t)b*TT + qb + lg*4 + j;
      #pragma unroll
      for (int n = 0; n < 4; n++)
        y[row*CC + h*HD + n*16 + lr] = f2bf(o[m][n][j] * ij);
    }
  }
}

// ---------------- launch ----------------
extern "C" void kernel_launch(void* const* d_in, const int* in_sizes, int n_in,
                              void* d_out, int out_size, void* d_ws, size_t ws_size,
                              hipStream_t stream){
  const float* x     = (const float*)d_in[0];
  const float* w_in  = (const float*)d_in[1];
  const float* w_out = (const float*)d_in[2];
  float* out = (float*)d_out;

  u16* xb   = (u16*)d_ws;                  // 8192*1024  (reused as y after GEMM1)
  u16* wib  = xb  + (size_t)MM * CC;       // 3072*1024
  u16* wob  = wib + (size_t)C3 * CC;       // 1024*1024
  u16* qkvb = wob + (size_t)CC * CC;       // 8192*3072
  u16* yb   = xb;                          // x is dead after GEMM1

  cvt_all<<<2048, 256, 0, stream>>>(x, w_in, w_out, xb);

  // GEMM1: 8192x3072x1024 -> grid 64x24 = 1536 blocks, 192/XCD
  gemm_bt<1><<<1536, 256, 0, stream>>>(xb, wib, (void*)qkvb, MM, C3, CC, 24, 192);
  attn_fwd<<<1024, 256, 0, stream>>>(qkvb, yb);
  // GEMM2: 8192x1024x1024 -> grid 64x8 = 512 blocks, 64/XCD
  gemm_bt<0><<<512, 256, 0, stream>>>(yb, wob, (void*)out, MM, CC, CC, 8, 64);
}

// Round 10
// 165.084 us; speedup vs baseline: 1.8721x; 1.0111x over previous
//
#include <hip/hip_runtime.h>
#include <stdint.h>

#define BB 4
#define TT 2048
#define CC 1024
#define HH 16
#define HD 64
#define C3 3072
#define MM (BB*TT)   // 8192 rows

typedef __bf16 bf16_t;
typedef bf16_t bf16x8 __attribute__((ext_vector_type(8)));
typedef float f32x4 __attribute__((ext_vector_type(4)));
typedef unsigned short u16;
typedef u16 u16x8 __attribute__((ext_vector_type(8)));
typedef uint32_t u32;

// f32 -> bf16 round-to-nearest-even
static __device__ __forceinline__ u16 f2bf(float f){
  u32 u = __builtin_bit_cast(u32, f);
  u32 r = (u + 0x7fffu + ((u >> 16) & 1u)) >> 16;
  return (u16)r;
}

static __device__ __forceinline__ f32x4 mfma16(bf16x8 a, bf16x8 b, f32x4 c){
  return __builtin_amdgcn_mfma_f32_16x16x32_bf16(a, b, c, 0, 0, 0);
}

typedef __attribute__((address_space(1))) void* gas_t;
typedef __attribute__((address_space(3))) void* las_t;
static __device__ __forceinline__ void gload16(const void* g, void* l){
  __builtin_amdgcn_global_load_lds((gas_t)g, (las_t)l, 16, 0, 0);
}

// ---------------- fp32 -> bf16 conversion (all three inputs, one kernel) -----
__global__ __launch_bounds__(256) void cvt_all(const float* __restrict__ x,
                                               const float* __restrict__ wi,
                                               const float* __restrict__ wo,
                                               u16* __restrict__ out){
  const int n1 = MM*CC/8, n2 = C3*CC/8, n3 = CC*CC/8;
  const int total = n1 + n2 + n3;
  int stride = gridDim.x * blockDim.x;
  for (int i = blockIdx.x * blockDim.x + threadIdx.x; i < total; i += stride){
    const float* src; int k;
    if (i < n1){ src = x; k = i; }
    else if (i < n1 + n2){ src = wi; k = i - n1; }
    else { src = wo; k = i - n1 - n2; }
    const float4* p = (const float4*)src + (size_t)k * 2;
    float4 a = p[0], b = p[1];
    u16x8 o;
    o[0]=f2bf(a.x); o[1]=f2bf(a.y); o[2]=f2bf(a.z); o[3]=f2bf(a.w);
    o[4]=f2bf(b.x); o[5]=f2bf(b.y); o[6]=f2bf(b.z); o[7]=f2bf(b.w);
    *((u16x8*)out + i) = o;
  }
}

// ---------------- bt-GEMM: C[M,N] = A[M,K] * B[N,K]^T ------------------------
// 128x128 tile, BK=64, 256 thr = 4 waves (2x2). LDS reads XOR-swizzled
// (slot ^= row&7) via pre-swizzled global source (gload_lds writes linearly).
// 1D grid with XCD-chunked swizzle: xcd = bid&7 owns cpx consecutive tiles.
template<int OUTBF>
__global__ __launch_bounds__(256) void gemm_bt(const u16* __restrict__ A,
                                               const u16* __restrict__ Bm,
                                               void* __restrict__ Cp,
                                               int M, int N, int K,
                                               int nbx, int cpx){
  __shared__ u16 As[128*64];
  __shared__ u16 Bs[128*64];
  const int bid = blockIdx.x;
  const int nb = (bid & 7) * cpx + (bid >> 3);
  const int by = nb / nbx, bx = nb - by * nbx;
  const int tid  = threadIdx.x;
  const int lane = tid & 63;
  const int w    = tid >> 6;
  const int m0   = by * 128;
  const int n0   = bx * 128;
  const int wm   = (w >> 1) * 64;
  const int wn   = (w & 1) * 64;
  const int lr   = lane & 15;
  const int lg4  = lane >> 4;        // 0..3

  f32x4 acc[4][4] = {};

  const int rq  = tid >> 3;                          // 0..31
  const int c8s = ((tid & 7) ^ (rq & 7)) * 8;        // pre-swizzled global col
  const u16* gA = A  + (size_t)(m0 + rq) * K + c8s;
  const u16* gB = Bm + (size_t)(n0 + rq) * K + c8s;
  char* lA = (char*)As + tid*16;
  char* lB = (char*)Bs + tid*16;

  for (int k0 = 0; k0 < K; k0 += 64){
    #pragma unroll
    for (int q = 0; q < 4; q++){
      gload16(gA + (size_t)(q*32)*K + k0, lA + q*4096);
      gload16(gB + (size_t)(q*32)*K + k0, lB + q*4096);
    }
    __syncthreads();
    #pragma unroll
    for (int kk = 0; kk < 2; kk++){
      bf16x8 af[4], bfr[4];
      #pragma unroll
      for (int m = 0; m < 4; m++){
        int row = wm + m*16 + lr;
        int slot = ((kk<<2) | lg4) ^ (row & 7);
        af[m] = *(const bf16x8*)((const char*)As + row*128 + slot*16);
      }
      #pragma unroll
      for (int n = 0; n < 4; n++){
        int row = wn + n*16 + lr;
        int slot = ((kk<<2) | lg4) ^ (row & 7);
        bfr[n] = *(const bf16x8*)((const char*)Bs + row*128 + slot*16);
      }
      #pragma unroll
      for (int m = 0; m < 4; m++)
        #pragma unroll
        for (int n = 0; n < 4; n++)
          acc[m][n] = mfma16(af[m], bfr[n], acc[m][n]);
    }
    __syncthreads();
  }

  const int cr = lg4 * 4;
  #pragma unroll
  for (int m = 0; m < 4; m++)
    #pragma unroll
    for (int n = 0; n < 4; n++)
      #pragma unroll
      for (int j = 0; j < 4; j++){
        size_t row = (size_t)(m0 + wm + m*16 + cr + j);
        size_t col = (size_t)(n0 + wn + n*16 + lr);
        if (OUTBF) ((u16*)Cp)[row*(size_t)N + col] = f2bf(acc[m][n][j]);
        else       ((float*)Cp)[row*(size_t)N + col] = acc[m][n][j];
      }
}

// ---------------- flash attention (causal), bf16 in/out ----------------
// Block = q-tile PAIR (tq, 31-tq), constant work. bid = h + 16b + 64tq so
// same-(b,h) blocks are stride-64 (same XCD -> one L2 copy of K/V).
// Swapped QK^T with PERMUTED K-rows; P-quads feed PV natively (no P LDS).
// V^T dc-XOR swizzle (col ^= 8*dc) kills the 4-way staging-write conflict.
// vb REGISTER PREFETCH: V fragments loaded right after QK issues, shared by
// both m-bodies -> PV is pure-register MFMA (no LDS latency after softmax).
__global__ __launch_bounds__(256, 2) void attn_fwd(const u16* __restrict__ qkv,
                                                   u16* __restrict__ y){
  __shared__ u16 Kl[2][64*72];   // K tile [k][d], row stride 72, XOR-swizzled
  __shared__ u16 Vt[2][64*72];   // V^T tile [d][k], row stride 72, dc-swizzled
  const int bid = blockIdx.x;
  const int tq = bid >> 6;
  const int h = bid & 15, b = (bid >> 4) & 3;
  const int tid = threadIdx.x, lane = tid & 63, w = tid >> 6;
  const int lr = lane & 15, lg = lane >> 4;
  const size_t base = (size_t)b * TT * C3;
  const int qA = tq*64 + w*16;          // m=0 wave q-base
  const int qB = (31-tq)*64 + w*16;     // m=1 wave q-base
  const float SC = 0.18033688011112042f;   // (1/8) * log2(e)

  // Q fragments (B-operand), pre-scaled by SC
  bf16x8 qf[2][2];
  {
    const u16* qp0 = qkv + base + (size_t)(qA + lr) * C3 + h*HD;
    qf[0][0] = *(const bf16x8*)(qp0 + lg*8);
    qf[0][1] = *(const bf16x8*)(qp0 + 32 + lg*8);
    const u16* qp1 = qkv + base + (size_t)(qB + lr) * C3 + h*HD;
    qf[1][0] = *(const bf16x8*)(qp1 + lg*8);
    qf[1][1] = *(const bf16x8*)(qp1 + 32 + lg*8);
    #pragma unroll
    for (int m = 0; m < 2; m++)
      #pragma unroll
      for (int i = 0; i < 2; i++)
        #pragma unroll
        for (int e = 0; e < 8; e++)
          qf[m][i][e] = (bf16_t)((float)qf[m][i][e] * SC);
  }

  // K staging: row = tid>>3 (coalesced);  V staging: adjacent k-row pair
  const int rK = tid >> 3, cK = tid & 7;
  const int rp = tid & 15;            // k-pair: rows 2rp, 2rp+1
  const int dc = (tid >> 4) & 7;      // d-chunk
  const int hf = tid >> 7;            // +32 k half
  const u16* gK = qkv + base + (size_t)rK * C3 + CC + h*HD + cK*8;
  const u16* gV = qkv + base + (size_t)(2*rp + 32*hf) * C3 + 2*CC + h*HD + dc*8;

  // swizzled K write indices (key = (row>>3)&1, same for row and row+32)
  const int kkey = ((rK >> 3) & 1) << 5;
  const int kw0 = rK*72 + ((cK*8) ^ kkey);
  const int kw1 = (rK+32)*72 + ((cK*8) ^ kkey);
  const int vcol = (2*rp + 32*hf) ^ (8*dc);   // V^T col, dc-swizzled

  // kb read: row rho(n,lr) -> key depends only on (lr>>2)&1
  const int rdx = ((lr >> 2) & 1) << 5;
  const int rbase = 8*(lr >> 2) + (lr & 3);     // row part from lr

  u16x8 kreg[2], vreg[2];
  kreg[0] = *(const u16x8*)(gK);
  kreg[1] = *(const u16x8*)(gK + (size_t)32*C3);
  vreg[0] = *(const u16x8*)(gV);
  vreg[1] = *(const u16x8*)(gV + C3);

  f32x4 o[2][4] = {};
  float mj[2] = {-1e30f, -1e30f};
  float lj[2] = {0.f, 0.f};

  const int ktmax = 31 - tq;
  for (int kt = 0; kt <= ktmax; kt++){
    const int cb = kt & 1;
    u16* KL = Kl[cb];
    u16* VT = Vt[cb];
    // stage current tile (regs -> LDS); overlaps other waves' prev compute
    *(u16x8*)&KL[kw0] = kreg[0];
    *(u16x8*)&KL[kw1] = kreg[1];
    #pragma unroll
    for (int e = 0; e < 8; e++){
      u32 pk = (u32)vreg[0][e] | ((u32)vreg[1][e] << 16);
      *(u32*)&VT[(dc*8+e)*72 + vcol] = pk;
    }
    __syncthreads();

    // prefetch next tile into regs (hides under compute)
    if (kt < ktmax){
      const u16* gk2 = gK + (size_t)(kt+1)*64*C3;
      const u16* gv2 = gV + (size_t)(kt+1)*64*C3;
      kreg[0] = *(const u16x8*)(gk2);
      kreg[1] = *(const u16x8*)(gk2 + (size_t)32*C3);
      vreg[0] = *(const u16x8*)(gv2);
      vreg[1] = *(const u16x8*)(gv2 + C3);
    }

    const bool m0act = (kt <= tq);
    bf16x8 vb[8];   // V fragments, loaded once per kt, shared by both m-bodies

    // sequential per-m: {QK, softmax, PV}; PV uses register-held V
    #pragma unroll
    for (int m = 1; m >= 0; m--){
      if (m == 0 && !m0act) continue;

      // S^T via permuted K-rows: lane holds S[q=lr][k=32(n>>1)+8lg+4(n&1)+j]
      f32x4 s[4] = {};
      __builtin_amdgcn_s_setprio(1);
      #pragma unroll
      for (int n = 0; n < 4; n++){
        const int rho = 32*(n>>1) + 4*(n&1) + rbase;
        bf16x8 kb0 = *(const bf16x8*)&KL[rho*72 + ((     lg*8) ^ rdx)];
        bf16x8 kb1 = *(const bf16x8*)&KL[rho*72 + ((32 + lg*8) ^ rdx)];
        s[n] = mfma16(kb0, qf[m][0], s[n]);
        s[n] = mfma16(kb1, qf[m][1], s[n]);
      }
      __builtin_amdgcn_s_setprio(0);

      if (m == 1){
        // issue V fragment loads now; they complete under the softmax
        #pragma unroll
        for (int n = 0; n < 4; n++){
          const int dcr = (2*n + (lr >> 3)) & 7;
          const int c0 = (lg ^ dcr) * 8;
          vb[2*n]   = *(const bf16x8*)&VT[(n*16+lr)*72 + c0];
          vb[2*n+1] = *(const bf16x8*)&VT[(n*16+lr)*72 + (c0 ^ 32)];
        }
      }

      // online softmax (scores pre-scaled): mask in place, tree reduce
      const int qrow = (m ? qB : qA) + lr;
      const bool dm = (kt == (m ? ktmax : tq));   // diagonal tile for this m
      if (dm){
        #pragma unroll
        for (int n = 0; n < 4; n++)
          #pragma unroll
          for (int j = 0; j < 4; j++)
            if (kt*64 + 32*(n>>1) + 8*lg + 4*(n&1) + j > qrow)
              s[n][j] = -1e30f;
      }
      float x0 = fmaxf(fmaxf(s[0][0], s[0][1]), fmaxf(s[0][2], s[0][3]));
      float x1 = fmaxf(fmaxf(s[1][0], s[1][1]), fmaxf(s[1][2], s[1][3]));
      float x2 = fmaxf(fmaxf(s[2][0], s[2][1]), fmaxf(s[2][2], s[2][3]));
      float x3 = fmaxf(fmaxf(s[3][0], s[3][1]), fmaxf(s[3][2], s[3][3]));
      float tm = fmaxf(fmaxf(x0, x1), fmaxf(x2, x3));
      tm = fmaxf(tm, __shfl_xor(tm, 16, 64));
      tm = fmaxf(tm, __shfl_xor(tm, 32, 64));
      float mo = mj[m];
      if (!__all(tm <= mo + 4.0f)){   // T13 defer-max, THR=4 (P <= 16)
        float mn = fmaxf(mo, tm);
        float al = __builtin_amdgcn_exp2f(mo - mn);
        mj[m] = mn;
        lj[m] *= al;
        float a0 = __shfl(al, lg*4+0, 16);
        float a1 = __shfl(al, lg*4+1, 16);
        float a2 = __shfl(al, lg*4+2, 16);
        float a3 = __shfl(al, lg*4+3, 16);
        #pragma unroll
        for (int n = 0; n < 4; n++){
          o[m][n][0] *= a0; o[m][n][1] *= a1;
          o[m][n][2] *= a2; o[m][n][3] *= a3;
        }
      }
      float mm = mj[m];
      float psn[4];
      bf16x8 pa, pb;
      #pragma unroll
      for (int n = 0; n < 4; n++){
        float p0 = __builtin_amdgcn_exp2f(s[n][0] - mm);
        float p1 = __builtin_amdgcn_exp2f(s[n][1] - mm);
        float p2 = __builtin_amdgcn_exp2f(s[n][2] - mm);
        float p3 = __builtin_amdgcn_exp2f(s[n][3] - mm);
        psn[n] = (p0 + p1) + (p2 + p3);
        if (n == 0){ pa[0]=(bf16_t)p0; pa[1]=(bf16_t)p1; pa[2]=(bf16_t)p2; pa[3]=(bf16_t)p3; }
        if (n == 1){ pa[4]=(bf16_t)p0; pa[5]=(bf16_t)p1; pa[6]=(bf16_t)p2; pa[7]=(bf16_t)p3; }
        if (n == 2){ pb[0]=(bf16_t)p0; pb[1]=(bf16_t)p1; pb[2]=(bf16_t)p2; pb[3]=(bf16_t)p3; }
        if (n == 3){ pb[4]=(bf16_t)p0; pb[5]=(bf16_t)p1; pb[6]=(bf16_t)p2; pb[7]=(bf16_t)p3; }
      }
      float ps = (psn[0] + psn[1]) + (psn[2] + psn[3]);
      ps += __shfl_xor(ps, 16, 64);
      ps += __shfl_xor(ps, 32, 64);
      lj[m] += ps;

      // O[m] += P V  (P and V straight from registers)
      __builtin_amdgcn_s_setprio(1);
      #pragma unroll
      for (int n = 0; n < 4; n++){
        o[m][n] = mfma16(pa, vb[2*n],   o[m][n]);
        o[m][n] = mfma16(pb, vb[2*n+1], o[m][n]);
      }
      __builtin_amdgcn_s_setprio(0);
    }
  }

  // normalize + write y (bf16); 1/l transposed to o's row layout via shfl
  #pragma unroll
  for (int m = 0; m < 2; m++){
    float inv = 1.0f / lj[m];
    float i0 = __shfl(inv, lg*4+0, 16);
    float i1 = __shfl(inv, lg*4+1, 16);
    float i2 = __shfl(inv, lg*4+2, 16);
    float i3 = __shfl(inv, lg*4+3, 16);
    const int qb = (m ? qB : qA);
    #pragma unroll
    for (int j = 0; j < 4; j++){
      float ij = (j==0) ? i0 : (j==1) ? i1 : (j==2) ? i2 : i3;
      size_t row = (size_t)b*TT + qb + lg*4 + j;
      #pragma unroll
      for (int n = 0; n < 4; n++)
        y[row*CC + h*HD + n*16 + lr] = f2bf(o[m][n][j] * ij);
    }
  }
}

// ---------------- launch ----------------
extern "C" void kernel_launch(void* const* d_in, const int* in_sizes, int n_in,
                              void* d_out, int out_size, void* d_ws, size_t ws_size,
                              hipStream_t stream){
  const float* x     = (const float*)d_in[0];
  const float* w_in  = (const float*)d_in[1];
  const float* w_out = (const float*)d_in[2];
  float* out = (float*)d_out;

  u16* xb   = (u16*)d_ws;                  // 8192*1024  (reused as y after GEMM1)
  u16* wib  = xb  + (size_t)MM * CC;       // 3072*1024
  u16* wob  = wib + (size_t)C3 * CC;       // 1024*1024
  u16* qkvb = wob + (size_t)CC * CC;       // 8192*3072
  u16* yb   = xb;                          // x is dead after GEMM1

  cvt_all<<<2048, 256, 0, stream>>>(x, w_in, w_out, xb);

  // GEMM1: 8192x3072x1024 -> grid 64x24 = 1536 blocks, 192/XCD
  gemm_bt<1><<<1536, 256, 0, stream>>>(xb, wib, (void*)qkvb, MM, C3, CC, 24, 192);
  attn_fwd<<<1024, 256, 0, stream>>>(qkvb, yb);
  // GEMM2: 8192x1024x1024 -> grid 64x8 = 512 blocks, 64/XCD
  gemm_bt<0><<<512, 256, 0, stream>>>(yb, wob, (void*)out, MM, CC, CC, 8, 64);
}